// Round 15
// baseline (273.001 us; speedup 1.0000x reference)
//
#include <hip/hip_runtime.h>
#include <hip/hip_bf16.h>
#include <stdint.h>

typedef __bf16 bf16_t;
typedef __bf16 bf16x8 __attribute__((ext_vector_type(8)));
typedef __bf16 bf16x4 __attribute__((ext_vector_type(4)));
typedef float  f32x4  __attribute__((ext_vector_type(4)));

#define DEV __device__ __forceinline__

static constexpr int NTOK = 2048;
static constexpr int DIM  = 1024;
static constexpr int NH   = 16;
static constexpr int DH   = 64;
static constexpr int SLOTS_PER_HEAD = 40;   // sum over Q=0..15 of ceil((Q+1)/4)
static constexpr int PART_SLOTS = 36;       // slots 4..39 go through part/merge
static constexpr int PART_STRIDE = 17408;   // 128x64 bf16 (16384) + m2[128] f32 + l[128] f32
static constexpr float L2E = 1.44269504f;

// LPT dispatch order: 28 eight-tile slots, then 6-tile, 4-tile, 2-tile
__device__ static constexpr unsigned char SLOT_ORDER[40] = {
    39, 38, 37, 36, 34, 33, 32, 30, 29, 28, 26, 25, 24, 23,
    22, 21, 19, 18, 16, 15, 13, 12, 11, 10, 8, 6, 4, 3,
    35, 20, 9, 2,   // 6-tile
    31, 17, 7, 1,   // 4-tile
    27, 14, 5, 0};  // 2-tile

DEV void gload_lds16(const void* g, void* l) {
  __builtin_amdgcn_global_load_lds(
      (__attribute__((address_space(1))) void*)(g),
      (__attribute__((address_space(3))) void*)(l), 16, 0, 0);
}

DEV float bf2f(bf16_t b) { return (float)b; }

// ---- fused: LayerNorm (0..2047) + w_qkv T (2048..2815) + w_out T (2816..3071)
//      + zero merge counters (block 3072) ----
__global__ __launch_bounds__(256) void k_ln_tc(const float* __restrict__ x,
                                               const float* __restrict__ gamma,
                                               const float* __restrict__ beta,
                                               bf16_t* __restrict__ xn,
                                               const float* __restrict__ wsrc,
                                               bf16_t* __restrict__ wdst,
                                               const float* __restrict__ wosrc,
                                               bf16_t* __restrict__ wodst,
                                               int* __restrict__ cnt) {
  __shared__ float tile[64][65];
  __shared__ float red[8];
  int b = blockIdx.x;
  if (b < NTOK) {
    const int row = b;
    const int t = threadIdx.x;
    const float4* x4 = reinterpret_cast<const float4*>(x);
    float4 v = x4[(size_t)row * 256 + t];
    float s  = v.x + v.y + v.z + v.w;
    float s2 = v.x * v.x + v.y * v.y + v.z * v.z + v.w * v.w;
#pragma unroll
    for (int o = 1; o < 64; o <<= 1) {
      s  += __shfl_xor(s, o, 64);
      s2 += __shfl_xor(s2, o, 64);
    }
    const int w = t >> 6, lane = t & 63;
    if (lane == 0) { red[w] = s; red[4 + w] = s2; }
    __syncthreads();
    s  = red[0] + red[1] + red[2] + red[3];
    s2 = red[4] + red[5] + red[6] + red[7];
    const float mu  = s * (1.0f / 1024.0f);
    const float var = s2 * (1.0f / 1024.0f) - mu * mu;
    const float inv = rsqrtf(var + 1e-6f);
    const float4 g = reinterpret_cast<const float4*>(gamma)[t];
    const float4 bb = reinterpret_cast<const float4*>(beta)[t];
    bf16x4 o;
    o[0] = (bf16_t)((v.x - mu) * inv * g.x + bb.x);
    o[1] = (bf16_t)((v.y - mu) * inv * g.y + bb.y);
    o[2] = (bf16_t)((v.z - mu) * inv * g.z + bb.z);
    o[3] = (bf16_t)((v.w - mu) * inv * g.w + bb.w);
    *reinterpret_cast<bf16x4*>(xn + (size_t)row * DIM + t * 4) = o;
  } else if (b < NTOK + 768) {
    b -= NTOK;
    const int c0 = (b % 48) * 64;          // N = 3072
    const int r0 = (b / 48) * 64;          // M = 1024
    const int tx = threadIdx.x & 63;
    const int ty = threadIdx.x >> 6;
#pragma unroll
    for (int i = 0; i < 16; ++i) {
      int r = ty + i * 4;
      tile[r][tx] = wsrc[(size_t)(r0 + r) * 3072 + c0 + tx];
    }
    __syncthreads();
#pragma unroll
    for (int i = 0; i < 16; ++i) {
      int r = ty + i * 4;
      wdst[(size_t)(c0 + r) * 1024 + r0 + tx] = (bf16_t)tile[tx][r];
    }
  } else if (b < NTOK + 768 + 256) {
    b -= (NTOK + 768);
    const int c0 = (b & 15) * 64;          // N = 1024
    const int r0 = (b >> 4) * 64;          // M = 1024
    const int tx = threadIdx.x & 63;
    const int ty = threadIdx.x >> 6;
#pragma unroll
    for (int i = 0; i < 16; ++i) {
      int r = ty + i * 4;
      tile[r][tx] = wosrc[(size_t)(r0 + r) * 1024 + c0 + tx];
    }
    __syncthreads();
#pragma unroll
    for (int i = 0; i < 16; ++i) {
      int r = ty + i * 4;
      wodst[(size_t)(c0 + r) * 1024 + r0 + tx] = (bf16_t)tile[tx][r];
    }
  } else {
    cnt[threadIdx.x] = 0;                  // 256 merge counters (192 used)
  }
}

// ---- QKV GEMM 128x128 (m97 layout), counted-vmcnt 2-phase + fused RoPE epilogue ----
// q cols -> Qp[2048][1024] (roped, *1/32); k cols -> Kp[h][n][64] (roped); v -> Vt[h][d][n]
__global__ __launch_bounds__(256) void k_gemm_qkv(const bf16_t* __restrict__ A,
                                                  const bf16_t* __restrict__ Bt,
                                                  bf16_t* __restrict__ Qp,
                                                  bf16_t* __restrict__ Kp,
                                                  bf16_t* __restrict__ Vt,
                                                  const float* __restrict__ psin,
                                                  const float* __restrict__ pcos) {
  __shared__ alignas(16) bf16_t As[2][128 * 32];   // 2 x 8 KB
  __shared__ alignas(16) bf16_t Bs[2][128 * 32];   // 2 x 8 KB
  const int K = DIM;
  const int tid = threadIdx.x, lane = tid & 63, w = tid >> 6;
  const int bm = blockIdx.x * 128, bn = blockIdx.y * 128;
  const int wr = (w >> 1) * 64, wc = (w & 1) * 64;
  f32x4 acc[4][4];
#pragma unroll
  for (int i = 0; i < 4; ++i)
#pragma unroll
    for (int j = 0; j < 4; ++j) acc[i][j] = f32x4{0.f, 0.f, 0.f, 0.f};

  const int srow  = lane >> 2;
  const int scol8 = (lane & 3) * 8;

#define GSTAGEQ(KT, BUF)                                                              \
  {                                                                                   \
    _Pragma("unroll") for (int it = 0; it < 2; ++it) {                                \
      int seg = w * 2 + it;                                                           \
      gload_lds16(A  + (size_t)(bm + seg * 16 + srow) * K + (KT) + scol8,             \
                  (char*)As + (BUF) * 8192 + seg * 1024 + lane * 16);                 \
      gload_lds16(Bt + (size_t)(bn + seg * 16 + srow) * K + (KT) + scol8,             \
                  (char*)Bs + (BUF) * 8192 + seg * 1024 + lane * 16);                 \
    }                                                                                 \
  }

  GSTAGEQ(0, 0)
  int buf = 0;
  for (int kt = 0; kt < K; kt += 32, buf ^= 1) {
    if (kt + 32 < K) {
      GSTAGEQ(kt + 32, buf ^ 1)
      asm volatile("s_waitcnt vmcnt(4)" ::: "memory");
    } else {
      asm volatile("s_waitcnt vmcnt(0)" ::: "memory");
    }
    __builtin_amdgcn_s_barrier();
    bf16x8 af[4], bfr[4];
#pragma unroll
    for (int i = 0; i < 4; ++i) {
      int mrow = wr + i * 16 + (lane & 15);
      af[i] = *reinterpret_cast<const bf16x8*>((const char*)As + buf * 8192 + mrow * 64 +
                                               (lane >> 4) * 16);
    }
#pragma unroll
    for (int j = 0; j < 4; ++j) {
      int nrow = wc + j * 16 + (lane & 15);
      bfr[j] = *reinterpret_cast<const bf16x8*>((const char*)Bs + buf * 8192 + nrow * 64 +
                                                (lane >> 4) * 16);
    }
#pragma unroll
    for (int i = 0; i < 4; ++i)
#pragma unroll
      for (int j = 0; j < 4; ++j)
        acc[i][j] = __builtin_amdgcn_mfma_f32_16x16x32_bf16(af[i], bfr[j], acc[i][j], 0, 0, 0);
    __builtin_amdgcn_s_barrier();
  }
#undef GSTAGEQ

  if (bn >= 2048) {
    // V columns -> Vt[h][d][n]
#pragma unroll
    for (int i = 0; i < 4; ++i)
#pragma unroll
      for (int j = 0; j < 4; ++j) {
        int d = bn - 2048 + wc + j * 16 + (lane & 15);
        int n0v = bm + wr + i * 16 + (lane >> 4) * 4;
        bf16x4 v4;
#pragma unroll
        for (int r = 0; r < 4; ++r) v4[r] = (bf16_t)acc[i][j][r];
        *reinterpret_cast<bf16x4*>(Vt + (size_t)d * NTOK + n0v) = v4;
      }
  } else {
    // q/k columns: rope rows >=1 (pairs are adjacent lanes), q scaled by 1/32
#pragma unroll
    for (int i = 0; i < 4; ++i)
#pragma unroll
      for (int j = 0; j < 4; ++j) {
        int nn = bn + wc + j * 16 + (lane & 15);
        int tt = (nn & 63) >> 1;
        bool isq = nn < 1024;
#pragma unroll
        for (int r = 0; r < 4; ++r) {
          int mm = bm + wr + i * 16 + (lane >> 4) * 4 + r;
          float v = acc[i][j][r];
          float p = __shfl_xor(v, 1, 64);
          int pidx = (mm >= 1 ? mm - 1 : 0) * 32 + tt;
          float sn = psin[pidx], cs = pcos[pidx];
          float roped = (nn & 1) ? (v * cs + p * sn) : (v * cs - p * sn);
          if (mm < 1) roped = v;
          if (isq && mm >= 1) roped *= 0.03125f;
          if (isq)
            Qp[(size_t)mm * DIM + nn] = (bf16_t)roped;
          else {
            int hh = (nn - 1024) >> 6, dd = nn & 63;
            Kp[((size_t)hh * NTOK + mm) * DH + dd] = (bf16_t)roped;
          }
        }
      }
  }
}

// ---- out GEMM 64x64, counted-vmcnt 2-phase (f32 out + bias), grid (32,16) ----
__global__ __launch_bounds__(256) void k_gemm64(const bf16_t* __restrict__ A,
                                                const bf16_t* __restrict__ Bt,
                                                float* __restrict__ Cf,
                                                const float* __restrict__ bias,
                                                int M, int N, int K) {
  __shared__ alignas(16) bf16_t As[2][64 * 32];    // 2 x 4 KB
  __shared__ alignas(16) bf16_t Bs[2][64 * 32];    // 2 x 4 KB
  const int tid = threadIdx.x, lane = tid & 63, w = tid >> 6;
  const int bm = blockIdx.x * 64, bn = blockIdx.y * 64;
  const int wr = (w >> 1) * 32, wc = (w & 1) * 32;
  f32x4 acc[2][2];
#pragma unroll
  for (int i = 0; i < 2; ++i)
#pragma unroll
    for (int j = 0; j < 2; ++j) acc[i][j] = f32x4{0.f, 0.f, 0.f, 0.f};

  const int srow  = lane >> 2;
  const int scol8 = (lane & 3) * 8;

#define GSTAGE64(KT, BUF)                                                             \
  {                                                                                   \
    _Pragma("unroll") for (int it = 0; it < 2; ++it) {                                \
      int s = w * 2 + it;                                                             \
      if (s < 4)                                                                      \
        gload_lds16(A + (size_t)(bm + s * 16 + srow) * K + (KT) + scol8,              \
                    (char*)As + (BUF) * 4096 + s * 1024 + lane * 16);                 \
      else                                                                            \
        gload_lds16(Bt + (size_t)(bn + (s - 4) * 16 + srow) * K + (KT) + scol8,       \
                    (char*)Bs + (BUF) * 4096 + (s - 4) * 1024 + lane * 16);           \
    }                                                                                 \
  }

  GSTAGE64(0, 0)
  int buf = 0;
  for (int kt = 0; kt < K; kt += 32, buf ^= 1) {
    if (kt + 32 < K) {
      GSTAGE64(kt + 32, buf ^ 1)
      asm volatile("s_waitcnt vmcnt(2)" ::: "memory");
    } else {
      asm volatile("s_waitcnt vmcnt(0)" ::: "memory");
    }
    __builtin_amdgcn_s_barrier();
    bf16x8 af[2], bfr[2];
#pragma unroll
    for (int i = 0; i < 2; ++i) {
      int mrow = wr + i * 16 + (lane & 15);
      af[i] = *reinterpret_cast<const bf16x8*>((const char*)As + buf * 4096 + mrow * 64 +
                                               (lane >> 4) * 16);
    }
#pragma unroll
    for (int j = 0; j < 2; ++j) {
      int nrow = wc + j * 16 + (lane & 15);
      bfr[j] = *reinterpret_cast<const bf16x8*>((const char*)Bs + buf * 4096 + nrow * 64 +
                                                (lane >> 4) * 16);
    }
#pragma unroll
    for (int i = 0; i < 2; ++i)
#pragma unroll
      for (int j = 0; j < 2; ++j)
        acc[i][j] = __builtin_amdgcn_mfma_f32_16x16x32_bf16(af[i], bfr[j], acc[i][j], 0, 0, 0);
    __builtin_amdgcn_s_barrier();
  }
#undef GSTAGE64

#pragma unroll
  for (int i = 0; i < 2; ++i)
#pragma unroll
    for (int j = 0; j < 2; ++j)
#pragma unroll
      for (int r = 0; r < 4; ++r) {
        int mm = bm + wr + i * 16 + (lane >> 4) * 4 + r;
        int nn = bn + wc + j * 16 + (lane & 15);
        Cf[(size_t)mm * N + nn] = acc[i][j][r] + bias[nn];
      }
}

// ---- flash attention partials (8 waves x 16 q-rows, swapped-operand in-lane softmax)
//      1-D LPT grid: idx = rank*16 + h; rank 0 = row-0 (first), ranks 1..40 via SLOT_ORDER
//      + last-block merge (threadfence+syncthreads+atomic, fixed ordering) ----
__global__ __launch_bounds__(512) void k_attn_part(const bf16_t* __restrict__ Qp,
                                                   const bf16_t* __restrict__ Kp,
                                                   const bf16_t* __restrict__ Vt,
                                                   const int* __restrict__ mask,
                                                   char* __restrict__ part,
                                                   bf16_t* __restrict__ Ob,
                                                   int* __restrict__ cnt) {
  __shared__ alignas(16) bf16_t Ks[2][64][64];   // 16 KB
  __shared__ alignas(16) bf16_t Vs[2][64][64];   // 16 KB
  __shared__ alignas(16) float padf[512];        //  2 KB
  __shared__ int isLast;

  const int idx = blockIdx.x;
  const int h = idx & 15;
  const int rank = idx >> 4;

  if (rank == 0) {
    // ---------------- row 0: attends ALL 2048 keys, q un-roped/un-scaled ----------------
    float* qv   = padf;              // 64 f32
    float* sbuf = (float*)Ks;        // 2048 f32
    float* red  = (float*)Vs;        // 8 f32
    float* red2 = (float*)Vs + 64;   // 512 f32
    const int t = threadIdx.x, lane = t & 63, w8 = t >> 6;
    if (t < 64) qv[t] = (float)Qp[h * DH + t];
    __syncthreads();
    float sm[4];
    float lmax = -1e30f;
#pragma unroll
    for (int p = 0; p < 4; ++p) {
      int j = p * 512 + t;
      const bf16_t* kr = Kp + ((size_t)h * NTOK + j) * DH;
      float s = 0.f;
#pragma unroll
      for (int u = 0; u < 8; ++u) {
        bf16x8 kv8 = *reinterpret_cast<const bf16x8*>(kr + u * 8);
#pragma unroll
        for (int e = 0; e < 8; ++e) s += qv[u * 8 + e] * (float)kv8[e];
      }
      bool padj = (j == 0) || (mask[j - 1] != 0);
      s = padj ? s * 0.03125f : -1e30f;
      sm[p] = s;
      lmax = fmaxf(lmax, s);
    }
#pragma unroll
    for (int o = 1; o < 64; o <<= 1) lmax = fmaxf(lmax, __shfl_xor(lmax, o, 64));
    if (lane == 0) red[w8] = lmax;
    __syncthreads();
    float M = red[0];
#pragma unroll
    for (int i = 1; i < 8; ++i) M = fmaxf(M, red[i]);
    __syncthreads();
    float ls = 0.f;
#pragma unroll
    for (int p = 0; p < 4; ++p) {
      float pe = __expf(sm[p] - M);
      sbuf[p * 512 + t] = pe;
      ls += pe;
    }
#pragma unroll
    for (int o = 1; o < 64; o <<= 1) ls += __shfl_xor(ls, o, 64);
    if (lane == 0) red[w8] = ls;
    __syncthreads();
    float L = red[0];
#pragma unroll
    for (int i = 1; i < 8; ++i) L += red[i];

    const int d = t & 63, qr = t >> 6;
    const bf16_t* vr = Vt + ((size_t)h * DH + d) * NTOK + qr * 256;
    float a = 0.f;
#pragma unroll 8
    for (int u = 0; u < 32; ++u) {
      bf16x8 v8 = *reinterpret_cast<const bf16x8*>(vr + u * 8);
#pragma unroll
      for (int e = 0; e < 8; ++e) a += sbuf[qr * 256 + u * 8 + e] * (float)v8[e];
    }
    red2[qr * 64 + d] = a;
    __syncthreads();
    if (t < 64) {
      float o = 0.f;
#pragma unroll
      for (int i = 0; i < 8; ++i) o += red2[i * 64 + t];
      Ob[h * DH + t] = (bf16_t)(o / L);
    }
    return;
  }

  const int slot = SLOT_ORDER[rank - 1];
  int gq;
  if (slot < 4) gq = 0; else if (slot < 12) gq = 1; else if (slot < 24) gq = 2; else gq = 3;
  const int tt = slot - 2 * gq * (gq + 1);
  const int Q = (gq << 2) + tt / (gq + 1);
  const int c2 = tt - (tt / (gq + 1)) * (gq + 1);
  const int q0 = Q * 128;
  const int kbeg = c2 * 512;
  const int kvlen = (Q + 1) * 128;
  const int klen = min(512, kvlen - kbeg);
  const int ntiles = klen >> 6;                 // 2,4,6,8
  const int nch = gq + 1;

  const int tid = threadIdx.x, lane = tid & 63, w = tid >> 6;
  const int g = lane >> 4;       // lane group
  const int c = lane & 15;       // q column

  for (int jr = tid; jr < klen; jr += 512) {
    int j = kbeg + jr;
    padf[jr] = (j == 0 || mask[j - 1] != 0) ? 1.f : 0.f;
  }

  const int iw = q0 + w * 16;
  bf16x8 qf[2];
  {
    const bf16_t* qp = Qp + (size_t)(iw + c) * DIM + h * DH + g * 8;
    qf[0] = *reinterpret_cast<const bf16x8*>(qp);
    qf[1] = *reinterpret_cast<const bf16x8*>(qp + 32);
  }
  bf16x8 ones;
#pragma unroll
  for (int e = 0; e < 8; ++e) ones[e] = (bf16_t)1.0f;

  float m_run = -1e30f, m2 = -1e30f;
  f32x4 acc[4], accl;
#pragma unroll
  for (int df = 0; df < 4; ++df) acc[df] = f32x4{0.f, 0.f, 0.f, 0.f};
  accl = f32x4{0.f, 0.f, 0.f, 0.f};

  const int r8 = lane >> 3;

#define STAGE(KB, BUF)                                                                   \
  {                                                                                      \
    _Pragma("unroll") for (int i2 = 0; i2 < 2; ++i2) {                                   \
      int s = w * 2 + i2;                                                                \
      int sw = (lane & 7) ^ r8 ^ ((s & 3) << 1);                                         \
      if (s < 8) {                                                                       \
        int row = s * 8 + r8;                                                            \
        gload_lds16(Kp + ((size_t)h * NTOK + (KB) + row) * DH + sw * 8,                  \
                    (char*)Ks + (BUF)*8192 + s * 1024 + lane * 16);                      \
      } else {                                                                           \
        int row = (s - 8) * 8 + r8;                                                      \
        gload_lds16(Vt + ((size_t)h * DH + row) * NTOK + (KB) + sw * 8,                  \
                    (char*)Vs + (BUF)*8192 + (s - 8) * 1024 + lane * 16);                \
      }                                                                                  \
    }                                                                                    \
  }

  STAGE(kbeg, 0)

  for (int it = 0; it < ntiles; ++it) {
    const int buf = it & 1;
    if (it + 1 < ntiles) {
      STAGE(kbeg + (it + 1) * 64, buf ^ 1)
      asm volatile("s_waitcnt vmcnt(2)" ::: "memory");
    } else {
      asm volatile("s_waitcnt vmcnt(0)" ::: "memory");
    }
    __builtin_amdgcn_s_barrier();

    const int k0 = kbeg + it * 64;
    if (k0 <= iw + 15) {
      const char* KsT = (const char*)Ks + buf * 8192;
      const char* VsT = (const char*)Vs + buf * 8192;

      f32x4 sfr[4];
      __builtin_amdgcn_s_setprio(1);
#pragma unroll
      for (int f = 0; f < 4; ++f) {
        int key7 = ((f & 1) * 4) | (c & 3);
        int key = (f >> 1) * 32 + (c >> 2) * 8 + key7;
        int phi = key7 ^ (((c >> 2) & 3) << 1);
        f32x4 s = f32x4{0.f, 0.f, 0.f, 0.f};
#pragma unroll
        for (int kd = 0; kd < 2; ++kd) {
          bf16x8 kf = *reinterpret_cast<const bf16x8*>(
              KsT + key * 128 + (((kd * 4 + g) ^ phi) << 4));
          s = __builtin_amdgcn_mfma_f32_16x16x32_bf16(kf, qf[kd], s, 0, 0, 0);
        }
        sfr[f] = s;
      }
      __builtin_amdgcn_s_setprio(0);

      float pm = fmaxf(fmaxf(sfr[0][0], sfr[0][1]), fmaxf(sfr[0][2], sfr[0][3]));
#pragma unroll
      for (int f = 1; f < 4; ++f)
        pm = fmaxf(pm, fmaxf(fmaxf(sfr[f][0], sfr[f][1]), fmaxf(sfr[f][2], sfr[f][3])));
      pm = fmaxf(pm, __shfl_xor(pm, 16, 64));
      pm = fmaxf(pm, __shfl_xor(pm, 32, 64));

      if (!__all(pm <= m_run + 8.f)) {
        float mnew = fmaxf(m_run, pm);
        float corr = __builtin_amdgcn_exp2f((m_run - mnew) * L2E);
        m_run = mnew;
        m2 = mnew * L2E;
#pragma unroll
        for (int r = 0; r < 4; ++r) {
          float cr = __shfl(corr, g * 4 + r, 64);
          accl[r] *= cr;
#pragma unroll
          for (int df = 0; df < 4; ++df) acc[df][r] *= cr;
        }
      }

      const bool needC = (k0 + 63 > iw);
      const int qlane = iw + c;
      bf16x8 pa[2];
#pragma unroll
      for (int f = 0; f < 4; ++f) {
        int jb = (k0 - kbeg) + (f >> 1) * 32 + g * 8 + (f & 1) * 4;
        f32x4 pad4 = *reinterpret_cast<const f32x4*>(padf + jb);
#pragma unroll
        for (int r = 0; r < 4; ++r) {
          float pe = __builtin_amdgcn_exp2f(__builtin_fmaf(sfr[f][r], L2E, -m2)) * pad4[r];
          if (needC) pe = (kbeg + jb + r <= qlane) ? pe : 0.f;
          pa[f >> 1][(f & 1) * 4 + r] = (bf16_t)pe;
        }
      }

      __builtin_amdgcn_s_setprio(1);
#pragma unroll
      for (int ks = 0; ks < 2; ++ks) {
        accl = __builtin_amdgcn_mfma_f32_16x16x32_bf16(pa[ks], ones, accl, 0, 0, 0);
#pragma unroll
        for (int df = 0; df < 4; ++df) {
          int d = df * 16 + c;
          int phv = (d & 7) ^ (((d >> 3) & 3) << 1);
          bf16x8 vf = *reinterpret_cast<const bf16x8*>(
              VsT + d * 128 + (((ks * 4 + g) ^ phv) << 4));
          acc[df] = __builtin_amdgcn_mfma_f32_16x16x32_bf16(pa[ks], vf, acc[df], 0, 0, 0);
        }
      }
      __builtin_amdgcn_s_setprio(0);
    }
    __builtin_amdgcn_s_barrier();
  }
#undef STAGE

  if (nch == 1) {
    // single-chunk Q (Q<4): normalize and write Ob directly; row 0 owned by row-0 path
#pragma unroll
    for (int r = 0; r < 4; ++r) {
      float inv = 1.0f / accl[r];
      int row = w * 16 + g * 4 + r;
#pragma unroll
      for (int df = 0; df < 4; ++df) {
        if (q0 + row != 0)
          Ob[(size_t)(q0 + row) * DIM + h * DH + df * 16 + c] = (bf16_t)(acc[df][r] * inv);
      }
    }
    return;
  }

  // write unnormalized partial
  char* pb = part + (size_t)(h * PART_SLOTS + (slot - 4)) * PART_STRIDE;
  {
    bf16_t* po = (bf16_t*)pb;
    float* pmo = (float*)(pb + 16384);
    float* plo = (float*)(pb + 16896);
    float mq[4];
#pragma unroll
    for (int r = 0; r < 4; ++r) mq[r] = __shfl(m2, g * 4 + r, 64);
#pragma unroll
    for (int df = 0; df < 4; ++df)
#pragma unroll
      for (int r = 0; r < 4; ++r) {
        int row = w * 16 + g * 4 + r;
        po[row * 64 + df * 16 + c] = (bf16_t)acc[df][r];
      }
    if (c == 0) {
#pragma unroll
      for (int r = 0; r < 4; ++r) {
        int row = w * 16 + g * 4 + r;
        pmo[row] = mq[r];      // log2 units
        plo[row] = accl[r];
      }
    }
  }

  // last-block merge: release = {all writes} -> threadfence (per-thread) -> syncthreads
  // -> tid0 device-scope atomic. Acquire = atomic result -> threadfence -> reads.
  __threadfence();
  __syncthreads();
  if (tid == 0) {
    int old = atomicAdd(&cnt[h * 16 + Q], 1);
    isLast = (old == nch - 1);
  }
  __syncthreads();
  if (!isLast) return;
  __threadfence();

  const int cum = 2 * gq * (gq + 1) + (Q & 3) * nch - 4;
  const int row = tid >> 2, qq = tid & 3;   // 128 rows x 4 quarters of 16 cols
  float a2[16];
#pragma unroll
  for (int e = 0; e < 16; ++e) a2[e] = 0.f;
  float M = -3e38f, L = 0.f;
  for (int cc = 0; cc < nch; ++cc) {
    const char* pc = part + (size_t)(h * PART_SLOTS + cum + cc) * PART_STRIDE;
    float mc = ((const float*)(pc + 16384))[row];
    float lc = ((const float*)(pc + 16896))[row];
    float Mn = fmaxf(M, mc);
    float sOld = __builtin_amdgcn_exp2f(M - Mn), sNew = __builtin_amdgcn_exp2f(mc - Mn);
    M = Mn;
    L = L * sOld + lc * sNew;
    const bf16_t* od = (const bf16_t*)pc + row * 64 + qq * 16;
#pragma unroll
    for (int e8 = 0; e8 < 2; ++e8) {
      bf16x8 o8 = *reinterpret_cast<const bf16x8*>(od + e8 * 8);
#pragma unroll
      for (int e = 0; e < 8; ++e)
        a2[e8 * 8 + e] = a2[e8 * 8 + e] * sOld + (float)o8[e] * sNew;
    }
  }
  const float inv = 1.0f / L;
  bf16_t* dst = Ob + (size_t)(Q * 128 + row) * DIM + h * DH + qq * 16;
#pragma unroll
  for (int e8 = 0; e8 < 2; ++e8) {
    bf16x8 r8o;
#pragma unroll
    for (int e = 0; e < 8; ++e) r8o[e] = (bf16_t)(a2[e8 * 8 + e] * inv);
    *reinterpret_cast<bf16x8*>(dst + e8 * 8) = r8o;
  }
}

// ---- host ----
extern "C" void kernel_launch(void* const* d_in, const int* in_sizes, int n_in,
                              void* d_out, int out_size, void* d_ws, size_t ws_size,
                              hipStream_t stream) {
  const float* x       = (const float*)d_in[0];
  const float* pos_sin = (const float*)d_in[1];
  const float* pos_cos = (const float*)d_in[2];
  const int*   mask    = (const int*)d_in[3];
  const float* ln_s    = (const float*)d_in[4];
  const float* ln_b    = (const float*)d_in[5];
  const float* w_qkv   = (const float*)d_in[6];
  const float* w_out   = (const float*)d_in[7];
  const float* b_out   = (const float*)d_in[8];
  float* out = (float*)d_out;
  int* cnt = (int*)d_out;   // merge counters in d_out head; final GEMM overwrites

  if (ws_size < 33554432u) return;

  char* ws = (char*)d_ws;
  bf16_t* Qp   = (bf16_t*)(ws + 0);           //  4 MiB: 2048x1024
  bf16_t* Kp   = (bf16_t*)(ws + 4194304);     //  4 MiB: 16x2048x64
  bf16_t* Vt   = (bf16_t*)(ws + 8388608);     //  4 MiB: 16x64x2048
  bf16_t* Ob   = (bf16_t*)(ws + 12582912);    //  4 MiB: 2048x1024
  bf16_t* Wot  = (bf16_t*)(ws + 16777216);    //  2 MiB, alive whole run
  bf16_t* xn   = (bf16_t*)(ws + 18874368);    //  4 MiB, dead after QKV gemm
  bf16_t* Wqt  = (bf16_t*)(ws + 23068672);    //  6 MiB, dead after QKV gemm
  char*   part = ws + 18874368;               // 10.03 MiB (16*36*17408), overlays xn/Wqt

  k_ln_tc<<<NTOK + 768 + 256 + 1, 256, 0, stream>>>(x, ln_s, ln_b, xn, w_qkv, Wqt,
                                                    w_out, Wot, cnt);
  k_gemm_qkv<<<dim3(16, 24), 256, 0, stream>>>(xn, Wqt, Qp, Kp, Vt, pos_sin, pos_cos);
  k_attn_part<<<16 * (SLOTS_PER_HEAD + 1), 512, 0, stream>>>(Qp, Kp, Vt, mask, part, Ob,
                                                             cnt);
  k_gemm64<<<dim3(32, 16), 256, 0, stream>>>(Ob, Wot, out, b_out, NTOK, DIM, DIM);
}

// Round 16
// 86.328 us; speedup vs baseline: 3.1624x; 3.1624x over previous
//
#include <hip/hip_runtime.h>
#include <hip/hip_bf16.h>
#include <stdint.h>

typedef __bf16 bf16_t;
typedef __bf16 bf16x8 __attribute__((ext_vector_type(8)));
typedef __bf16 bf16x4 __attribute__((ext_vector_type(4)));
typedef float  f32x4  __attribute__((ext_vector_type(4)));

#define DEV __device__ __forceinline__

static constexpr int NTOK = 2048;
static constexpr int DIM  = 1024;
static constexpr int NH   = 16;
static constexpr int DH   = 64;
static constexpr int SLOTS_PER_HEAD = 40;   // sum over Q=0..15 of ceil((Q+1)/4)
static constexpr int PART_SLOTS = 36;       // slots 4..39 go through part/merge
static constexpr int PART_STRIDE = 17408;   // 128x64 bf16 (16384) + m2[128] f32 + l[128] f32
static constexpr float L2E = 1.44269504f;

// LPT dispatch order: 28 eight-tile slots, then 6-tile, 4-tile, 2-tile
__device__ static constexpr unsigned char SLOT_ORDER[40] = {
    39, 38, 37, 36, 34, 33, 32, 30, 29, 28, 26, 25, 24, 23,
    22, 21, 19, 18, 16, 15, 13, 12, 11, 10, 8, 6, 4, 3,
    35, 20, 9, 2,   // 6-tile
    31, 17, 7, 1,   // 4-tile
    27, 14, 5, 0};  // 2-tile

DEV void gload_lds16(const void* g, void* l) {
  __builtin_amdgcn_global_load_lds(
      (__attribute__((address_space(1))) void*)(g),
      (__attribute__((address_space(3))) void*)(l), 16, 0, 0);
}

DEV float bf2f(bf16_t b) { return (float)b; }

// ---- fused: LayerNorm (0..2047) + w_qkv T (2048..2815) + w_out T (2816..3071) ----
__global__ __launch_bounds__(256) void k_ln_tc(const float* __restrict__ x,
                                               const float* __restrict__ gamma,
                                               const float* __restrict__ beta,
                                               bf16_t* __restrict__ xn,
                                               const float* __restrict__ wsrc,
                                               bf16_t* __restrict__ wdst,
                                               const float* __restrict__ wosrc,
                                               bf16_t* __restrict__ wodst) {
  __shared__ float tile[64][65];
  __shared__ float red[8];
  int b = blockIdx.x;
  if (b < NTOK) {
    const int row = b;
    const int t = threadIdx.x;
    const float4* x4 = reinterpret_cast<const float4*>(x);
    float4 v = x4[(size_t)row * 256 + t];
    float s  = v.x + v.y + v.z + v.w;
    float s2 = v.x * v.x + v.y * v.y + v.z * v.z + v.w * v.w;
#pragma unroll
    for (int o = 1; o < 64; o <<= 1) {
      s  += __shfl_xor(s, o, 64);
      s2 += __shfl_xor(s2, o, 64);
    }
    const int w = t >> 6, lane = t & 63;
    if (lane == 0) { red[w] = s; red[4 + w] = s2; }
    __syncthreads();
    s  = red[0] + red[1] + red[2] + red[3];
    s2 = red[4] + red[5] + red[6] + red[7];
    const float mu  = s * (1.0f / 1024.0f);
    const float var = s2 * (1.0f / 1024.0f) - mu * mu;
    const float inv = rsqrtf(var + 1e-6f);
    const float4 g = reinterpret_cast<const float4*>(gamma)[t];
    const float4 bb = reinterpret_cast<const float4*>(beta)[t];
    bf16x4 o;
    o[0] = (bf16_t)((v.x - mu) * inv * g.x + bb.x);
    o[1] = (bf16_t)((v.y - mu) * inv * g.y + bb.y);
    o[2] = (bf16_t)((v.z - mu) * inv * g.z + bb.z);
    o[3] = (bf16_t)((v.w - mu) * inv * g.w + bb.w);
    *reinterpret_cast<bf16x4*>(xn + (size_t)row * DIM + t * 4) = o;
  } else if (b < NTOK + 768) {
    b -= NTOK;
    const int c0 = (b % 48) * 64;          // N = 3072
    const int r0 = (b / 48) * 64;          // M = 1024
    const int tx = threadIdx.x & 63;
    const int ty = threadIdx.x >> 6;
#pragma unroll
    for (int i = 0; i < 16; ++i) {
      int r = ty + i * 4;
      tile[r][tx] = wsrc[(size_t)(r0 + r) * 3072 + c0 + tx];
    }
    __syncthreads();
#pragma unroll
    for (int i = 0; i < 16; ++i) {
      int r = ty + i * 4;
      wdst[(size_t)(c0 + r) * 1024 + r0 + tx] = (bf16_t)tile[tx][r];
    }
  } else {
    b -= (NTOK + 768);
    const int c0 = (b & 15) * 64;          // N = 1024
    const int r0 = (b >> 4) * 64;          // M = 1024
    const int tx = threadIdx.x & 63;
    const int ty = threadIdx.x >> 6;
#pragma unroll
    for (int i = 0; i < 16; ++i) {
      int r = ty + i * 4;
      tile[r][tx] = wosrc[(size_t)(r0 + r) * 1024 + c0 + tx];
    }
    __syncthreads();
#pragma unroll
    for (int i = 0; i < 16; ++i) {
      int r = ty + i * 4;
      wodst[(size_t)(c0 + r) * 1024 + r0 + tx] = (bf16_t)tile[tx][r];
    }
  }
}

// ---- QKV GEMM 128x128 (m97 layout), counted-vmcnt 2-phase + fused RoPE epilogue ----
// q cols -> Qp[2048][1024] (roped, *1/32); k cols -> Kp[h][n][64] (roped); v -> Vt[h][d][n]
__global__ __launch_bounds__(256) void k_gemm_qkv(const bf16_t* __restrict__ A,
                                                  const bf16_t* __restrict__ Bt,
                                                  bf16_t* __restrict__ Qp,
                                                  bf16_t* __restrict__ Kp,
                                                  bf16_t* __restrict__ Vt,
                                                  const float* __restrict__ psin,
                                                  const float* __restrict__ pcos) {
  __shared__ alignas(16) bf16_t As[2][128 * 32];   // 2 x 8 KB
  __shared__ alignas(16) bf16_t Bs[2][128 * 32];   // 2 x 8 KB
  const int K = DIM;
  const int tid = threadIdx.x, lane = tid & 63, w = tid >> 6;
  const int bm = blockIdx.x * 128, bn = blockIdx.y * 128;
  const int wr = (w >> 1) * 64, wc = (w & 1) * 64;
  f32x4 acc[4][4];
#pragma unroll
  for (int i = 0; i < 4; ++i)
#pragma unroll
    for (int j = 0; j < 4; ++j) acc[i][j] = f32x4{0.f, 0.f, 0.f, 0.f};

  const int srow  = lane >> 2;
  const int scol8 = (lane & 3) * 8;

#define GSTAGEQ(KT, BUF)                                                              \
  {                                                                                   \
    _Pragma("unroll") for (int it = 0; it < 2; ++it) {                                \
      int seg = w * 2 + it;                                                           \
      gload_lds16(A  + (size_t)(bm + seg * 16 + srow) * K + (KT) + scol8,             \
                  (char*)As + (BUF) * 8192 + seg * 1024 + lane * 16);                 \
      gload_lds16(Bt + (size_t)(bn + seg * 16 + srow) * K + (KT) + scol8,             \
                  (char*)Bs + (BUF) * 8192 + seg * 1024 + lane * 16);                 \
    }                                                                                 \
  }

  GSTAGEQ(0, 0)
  int buf = 0;
  for (int kt = 0; kt < K; kt += 32, buf ^= 1) {
    if (kt + 32 < K) {
      GSTAGEQ(kt + 32, buf ^ 1)
      asm volatile("s_waitcnt vmcnt(4)" ::: "memory");
    } else {
      asm volatile("s_waitcnt vmcnt(0)" ::: "memory");
    }
    __builtin_amdgcn_s_barrier();
    bf16x8 af[4], bfr[4];
#pragma unroll
    for (int i = 0; i < 4; ++i) {
      int mrow = wr + i * 16 + (lane & 15);
      af[i] = *reinterpret_cast<const bf16x8*>((const char*)As + buf * 8192 + mrow * 64 +
                                               (lane >> 4) * 16);
    }
#pragma unroll
    for (int j = 0; j < 4; ++j) {
      int nrow = wc + j * 16 + (lane & 15);
      bfr[j] = *reinterpret_cast<const bf16x8*>((const char*)Bs + buf * 8192 + nrow * 64 +
                                                (lane >> 4) * 16);
    }
#pragma unroll
    for (int i = 0; i < 4; ++i)
#pragma unroll
      for (int j = 0; j < 4; ++j)
        acc[i][j] = __builtin_amdgcn_mfma_f32_16x16x32_bf16(af[i], bfr[j], acc[i][j], 0, 0, 0);
    __builtin_amdgcn_s_barrier();
  }
#undef GSTAGEQ

  if (bn >= 2048) {
    // V columns -> Vt[h][d][n]
#pragma unroll
    for (int i = 0; i < 4; ++i)
#pragma unroll
      for (int j = 0; j < 4; ++j) {
        int d = bn - 2048 + wc + j * 16 + (lane & 15);
        int n0v = bm + wr + i * 16 + (lane >> 4) * 4;
        bf16x4 v4;
#pragma unroll
        for (int r = 0; r < 4; ++r) v4[r] = (bf16_t)acc[i][j][r];
        *reinterpret_cast<bf16x4*>(Vt + (size_t)d * NTOK + n0v) = v4;
      }
  } else {
    // q/k columns: rope rows >=1 (pairs are adjacent lanes), q scaled by 1/32
#pragma unroll
    for (int i = 0; i < 4; ++i)
#pragma unroll
      for (int j = 0; j < 4; ++j) {
        int nn = bn + wc + j * 16 + (lane & 15);
        int tt = (nn & 63) >> 1;
        bool isq = nn < 1024;
#pragma unroll
        for (int r = 0; r < 4; ++r) {
          int mm = bm + wr + i * 16 + (lane >> 4) * 4 + r;
          float v = acc[i][j][r];
          float p = __shfl_xor(v, 1, 64);
          int pidx = (mm >= 1 ? mm - 1 : 0) * 32 + tt;
          float sn = psin[pidx], cs = pcos[pidx];
          float roped = (nn & 1) ? (v * cs + p * sn) : (v * cs - p * sn);
          if (mm < 1) roped = v;
          if (isq && mm >= 1) roped *= 0.03125f;
          if (isq)
            Qp[(size_t)mm * DIM + nn] = (bf16_t)roped;
          else {
            int hh = (nn - 1024) >> 6, dd = nn & 63;
            Kp[((size_t)hh * NTOK + mm) * DH + dd] = (bf16_t)roped;
          }
        }
      }
  }
}

// ---- out GEMM 64x64, counted-vmcnt 2-phase (f32 out + bias), grid (32,16) ----
__global__ __launch_bounds__(256) void k_gemm64(const bf16_t* __restrict__ A,
                                                const bf16_t* __restrict__ Bt,
                                                float* __restrict__ Cf,
                                                const float* __restrict__ bias,
                                                int M, int N, int K) {
  __shared__ alignas(16) bf16_t As[2][64 * 32];    // 2 x 4 KB
  __shared__ alignas(16) bf16_t Bs[2][64 * 32];    // 2 x 4 KB
  const int tid = threadIdx.x, lane = tid & 63, w = tid >> 6;
  const int bm = blockIdx.x * 64, bn = blockIdx.y * 64;
  const int wr = (w >> 1) * 32, wc = (w & 1) * 32;
  f32x4 acc[2][2];
#pragma unroll
  for (int i = 0; i < 2; ++i)
#pragma unroll
    for (int j = 0; j < 2; ++j) acc[i][j] = f32x4{0.f, 0.f, 0.f, 0.f};

  const int srow  = lane >> 2;
  const int scol8 = (lane & 3) * 8;

#define GSTAGE64(KT, BUF)                                                             \
  {                                                                                   \
    _Pragma("unroll") for (int it = 0; it < 2; ++it) {                                \
      int s = w * 2 + it;                                                             \
      if (s < 4)                                                                      \
        gload_lds16(A + (size_t)(bm + s * 16 + srow) * K + (KT) + scol8,              \
                    (char*)As + (BUF) * 4096 + s * 1024 + lane * 16);                 \
      else                                                                            \
        gload_lds16(Bt + (size_t)(bn + (s - 4) * 16 + srow) * K + (KT) + scol8,       \
                    (char*)Bs + (BUF) * 4096 + (s - 4) * 1024 + lane * 16);           \
    }                                                                                 \
  }

  GSTAGE64(0, 0)
  int buf = 0;
  for (int kt = 0; kt < K; kt += 32, buf ^= 1) {
    if (kt + 32 < K) {
      GSTAGE64(kt + 32, buf ^ 1)
      asm volatile("s_waitcnt vmcnt(2)" ::: "memory");
    } else {
      asm volatile("s_waitcnt vmcnt(0)" ::: "memory");
    }
    __builtin_amdgcn_s_barrier();
    bf16x8 af[2], bfr[2];
#pragma unroll
    for (int i = 0; i < 2; ++i) {
      int mrow = wr + i * 16 + (lane & 15);
      af[i] = *reinterpret_cast<const bf16x8*>((const char*)As + buf * 4096 + mrow * 64 +
                                               (lane >> 4) * 16);
    }
#pragma unroll
    for (int j = 0; j < 2; ++j) {
      int nrow = wc + j * 16 + (lane & 15);
      bfr[j] = *reinterpret_cast<const bf16x8*>((const char*)Bs + buf * 4096 + nrow * 64 +
                                                (lane >> 4) * 16);
    }
#pragma unroll
    for (int i = 0; i < 2; ++i)
#pragma unroll
      for (int j = 0; j < 2; ++j)
        acc[i][j] = __builtin_amdgcn_mfma_f32_16x16x32_bf16(af[i], bfr[j], acc[i][j], 0, 0, 0);
    __builtin_amdgcn_s_barrier();
  }
#undef GSTAGE64

#pragma unroll
  for (int i = 0; i < 2; ++i)
#pragma unroll
    for (int j = 0; j < 2; ++j)
#pragma unroll
      for (int r = 0; r < 4; ++r) {
        int mm = bm + wr + i * 16 + (lane >> 4) * 4 + r;
        int nn = bn + wc + j * 16 + (lane & 15);
        Cf[(size_t)mm * N + nn] = acc[i][j][r] + bias[nn];
      }
}

// ---- flash attention partials (8 waves x 16 q-rows, swapped-operand in-lane softmax)
//      1-D LPT grid: idx = rank*16 + h; rank 0 = row-0 (first), ranks 1..40 via SLOT_ORDER ----
__global__ __launch_bounds__(512) void k_attn_part(const bf16_t* __restrict__ Qp,
                                                   const bf16_t* __restrict__ Kp,
                                                   const bf16_t* __restrict__ Vt,
                                                   const int* __restrict__ mask,
                                                   char* __restrict__ part,
                                                   bf16_t* __restrict__ Ob) {
  __shared__ alignas(16) bf16_t Ks[2][64][64];   // 16 KB
  __shared__ alignas(16) bf16_t Vs[2][64][64];   // 16 KB
  __shared__ alignas(16) float padf[512];        //  2 KB

  const int idx = blockIdx.x;
  const int h = idx & 15;
  const int rank = idx >> 4;

  if (rank == 0) {
    // ---------------- row 0: attends ALL 2048 keys, q un-roped/un-scaled ----------------
    float* qv   = padf;              // 64 f32
    float* sbuf = (float*)Ks;        // 2048 f32
    float* red  = (float*)Vs;        // 8 f32
    float* red2 = (float*)Vs + 64;   // 512 f32
    const int t = threadIdx.x, lane = t & 63, w8 = t >> 6;
    if (t < 64) qv[t] = (float)Qp[h * DH + t];
    __syncthreads();
    float sm[4];
    float lmax = -1e30f;
#pragma unroll
    for (int p = 0; p < 4; ++p) {
      int j = p * 512 + t;
      const bf16_t* kr = Kp + ((size_t)h * NTOK + j) * DH;
      float s = 0.f;
#pragma unroll
      for (int u = 0; u < 8; ++u) {
        bf16x8 kv8 = *reinterpret_cast<const bf16x8*>(kr + u * 8);
#pragma unroll
        for (int e = 0; e < 8; ++e) s += qv[u * 8 + e] * (float)kv8[e];
      }
      bool padj = (j == 0) || (mask[j - 1] != 0);
      s = padj ? s * 0.03125f : -1e30f;
      sm[p] = s;
      lmax = fmaxf(lmax, s);
    }
#pragma unroll
    for (int o = 1; o < 64; o <<= 1) lmax = fmaxf(lmax, __shfl_xor(lmax, o, 64));
    if (lane == 0) red[w8] = lmax;
    __syncthreads();
    float M = red[0];
#pragma unroll
    for (int i = 1; i < 8; ++i) M = fmaxf(M, red[i]);
    __syncthreads();
    float ls = 0.f;
#pragma unroll
    for (int p = 0; p < 4; ++p) {
      float pe = __expf(sm[p] - M);
      sbuf[p * 512 + t] = pe;
      ls += pe;
    }
#pragma unroll
    for (int o = 1; o < 64; o <<= 1) ls += __shfl_xor(ls, o, 64);
    if (lane == 0) red[w8] = ls;
    __syncthreads();
    float L = red[0];
#pragma unroll
    for (int i = 1; i < 8; ++i) L += red[i];

    const int d = t & 63, qr = t >> 6;
    const bf16_t* vr = Vt + ((size_t)h * DH + d) * NTOK + qr * 256;
    float a = 0.f;
#pragma unroll 8
    for (int u = 0; u < 32; ++u) {
      bf16x8 v8 = *reinterpret_cast<const bf16x8*>(vr + u * 8);
#pragma unroll
      for (int e = 0; e < 8; ++e) a += sbuf[qr * 256 + u * 8 + e] * (float)v8[e];
    }
    red2[qr * 64 + d] = a;
    __syncthreads();
    if (t < 64) {
      float o = 0.f;
#pragma unroll
      for (int i = 0; i < 8; ++i) o += red2[i * 64 + t];
      Ob[h * DH + t] = (bf16_t)(o / L);
    }
    return;
  }

  const int slot = SLOT_ORDER[rank - 1];
  int gq;
  if (slot < 4) gq = 0; else if (slot < 12) gq = 1; else if (slot < 24) gq = 2; else gq = 3;
  const int tt = slot - 2 * gq * (gq + 1);
  const int Q = (gq << 2) + tt / (gq + 1);
  const int c2 = tt - (tt / (gq + 1)) * (gq + 1);
  const int q0 = Q * 128;
  const int kbeg = c2 * 512;
  const int kvlen = (Q + 1) * 128;
  const int klen = min(512, kvlen - kbeg);
  const int ntiles = klen >> 6;                 // 2,4,6,8
  const int nch = gq + 1;

  const int tid = threadIdx.x, lane = tid & 63, w = tid >> 6;
  const int g = lane >> 4;       // lane group
  const int c = lane & 15;       // q column

  for (int jr = tid; jr < klen; jr += 512) {
    int j = kbeg + jr;
    padf[jr] = (j == 0 || mask[j - 1] != 0) ? 1.f : 0.f;
  }

  const int iw = q0 + w * 16;
  bf16x8 qf[2];
  {
    const bf16_t* qp = Qp + (size_t)(iw + c) * DIM + h * DH + g * 8;
    qf[0] = *reinterpret_cast<const bf16x8*>(qp);
    qf[1] = *reinterpret_cast<const bf16x8*>(qp + 32);
  }
  bf16x8 ones;
#pragma unroll
  for (int e = 0; e < 8; ++e) ones[e] = (bf16_t)1.0f;

  float m_run = -1e30f, m2 = -1e30f;
  f32x4 acc[4], accl;
#pragma unroll
  for (int df = 0; df < 4; ++df) acc[df] = f32x4{0.f, 0.f, 0.f, 0.f};
  accl = f32x4{0.f, 0.f, 0.f, 0.f};

  const int r8 = lane >> 3;

#define STAGE(KB, BUF)                                                                   \
  {                                                                                      \
    _Pragma("unroll") for (int i2 = 0; i2 < 2; ++i2) {                                   \
      int s = w * 2 + i2;                                                                \
      int sw = (lane & 7) ^ r8 ^ ((s & 3) << 1);                                         \
      if (s < 8) {                                                                       \
        int row = s * 8 + r8;                                                            \
        gload_lds16(Kp + ((size_t)h * NTOK + (KB) + row) * DH + sw * 8,                  \
                    (char*)Ks + (BUF)*8192 + s * 1024 + lane * 16);                      \
      } else {                                                                           \
        int row = (s - 8) * 8 + r8;                                                      \
        gload_lds16(Vt + ((size_t)h * DH + row) * NTOK + (KB) + sw * 8,                  \
                    (char*)Vs + (BUF)*8192 + (s - 8) * 1024 + lane * 16);                \
      }                                                                                  \
    }                                                                                    \
  }

  STAGE(kbeg, 0)

  for (int it = 0; it < ntiles; ++it) {
    const int buf = it & 1;
    if (it + 1 < ntiles) {
      STAGE(kbeg + (it + 1) * 64, buf ^ 1)
      asm volatile("s_waitcnt vmcnt(2)" ::: "memory");
    } else {
      asm volatile("s_waitcnt vmcnt(0)" ::: "memory");
    }
    __builtin_amdgcn_s_barrier();

    const int k0 = kbeg + it * 64;
    if (k0 <= iw + 15) {
      const char* KsT = (const char*)Ks + buf * 8192;
      const char* VsT = (const char*)Vs + buf * 8192;

      f32x4 sfr[4];
      __builtin_amdgcn_s_setprio(1);
#pragma unroll
      for (int f = 0; f < 4; ++f) {
        int key7 = ((f & 1) * 4) | (c & 3);
        int key = (f >> 1) * 32 + (c >> 2) * 8 + key7;
        int phi = key7 ^ (((c >> 2) & 3) << 1);
        f32x4 s = f32x4{0.f, 0.f, 0.f, 0.f};
#pragma unroll
        for (int kd = 0; kd < 2; ++kd) {
          bf16x8 kf = *reinterpret_cast<const bf16x8*>(
              KsT + key * 128 + (((kd * 4 + g) ^ phi) << 4));
          s = __builtin_amdgcn_mfma_f32_16x16x32_bf16(kf, qf[kd], s, 0, 0, 0);
        }
        sfr[f] = s;
      }
      __builtin_amdgcn_s_setprio(0);

      float pm = fmaxf(fmaxf(sfr[0][0], sfr[0][1]), fmaxf(sfr[0][2], sfr[0][3]));
#pragma unroll
      for (int f = 1; f < 4; ++f)
        pm = fmaxf(pm, fmaxf(fmaxf(sfr[f][0], sfr[f][1]), fmaxf(sfr[f][2], sfr[f][3])));
      pm = fmaxf(pm, __shfl_xor(pm, 16, 64));
      pm = fmaxf(pm, __shfl_xor(pm, 32, 64));

      if (!__all(pm <= m_run + 8.f)) {
        float mnew = fmaxf(m_run, pm);
        float corr = __builtin_amdgcn_exp2f((m_run - mnew) * L2E);
        m_run = mnew;
        m2 = mnew * L2E;
#pragma unroll
        for (int r = 0; r < 4; ++r) {
          float cr = __shfl(corr, g * 4 + r, 64);
          accl[r] *= cr;
#pragma unroll
          for (int df = 0; df < 4; ++df) acc[df][r] *= cr;
        }
      }

      const bool needC = (k0 + 63 > iw);
      const int qlane = iw + c;
      bf16x8 pa[2];
#pragma unroll
      for (int f = 0; f < 4; ++f) {
        int jb = (k0 - kbeg) + (f >> 1) * 32 + g * 8 + (f & 1) * 4;
        f32x4 pad4 = *reinterpret_cast<const f32x4*>(padf + jb);
#pragma unroll
        for (int r = 0; r < 4; ++r) {
          float pe = __builtin_amdgcn_exp2f(__builtin_fmaf(sfr[f][r], L2E, -m2)) * pad4[r];
          if (needC) pe = (kbeg + jb + r <= qlane) ? pe : 0.f;
          pa[f >> 1][(f & 1) * 4 + r] = (bf16_t)pe;
        }
      }

      __builtin_amdgcn_s_setprio(1);
#pragma unroll
      for (int ks = 0; ks < 2; ++ks) {
        accl = __builtin_amdgcn_mfma_f32_16x16x32_bf16(pa[ks], ones, accl, 0, 0, 0);
#pragma unroll
        for (int df = 0; df < 4; ++df) {
          int d = df * 16 + c;
          int phv = (d & 7) ^ (((d >> 3) & 3) << 1);
          bf16x8 vf = *reinterpret_cast<const bf16x8*>(
              VsT + d * 128 + (((ks * 4 + g) ^ phv) << 4));
          acc[df] = __builtin_amdgcn_mfma_f32_16x16x32_bf16(pa[ks], vf, acc[df], 0, 0, 0);
        }
      }
      __builtin_amdgcn_s_setprio(0);
    }
    __builtin_amdgcn_s_barrier();
  }
#undef STAGE

  if (nch == 1) {
    // single-chunk Q (Q<4): normalize and write Ob directly; row 0 owned by row-0 path
#pragma unroll
    for (int r = 0; r < 4; ++r) {
      float inv = 1.0f / accl[r];
      int row = w * 16 + g * 4 + r;
#pragma unroll
      for (int df = 0; df < 4; ++df) {
        if (q0 + row != 0)
          Ob[(size_t)(q0 + row) * DIM + h * DH + df * 16 + c] = (bf16_t)(acc[df][r] * inv);
      }
    }
    return;
  }

  // write unnormalized partial (merged by separate k_merge kernel)
  char* pb = part + (size_t)(h * PART_SLOTS + (slot - 4)) * PART_STRIDE;
  bf16_t* po = (bf16_t*)pb;
  float* pmo = (float*)(pb + 16384);
  float* plo = (float*)(pb + 16896);
  float mq[4];
#pragma unroll
  for (int r = 0; r < 4; ++r) mq[r] = __shfl(m2, g * 4 + r, 64);
#pragma unroll
  for (int df = 0; df < 4; ++df)
#pragma unroll
    for (int r = 0; r < 4; ++r) {
      int row = w * 16 + g * 4 + r;
      po[row * 64 + df * 16 + c] = (bf16_t)acc[df][r];
    }
  if (c == 0) {
#pragma unroll
    for (int r = 0; r < 4; ++r) {
      int row = w * 16 + g * 4 + r;
      pmo[row] = mq[r];      // log2 units
      plo[row] = accl[r];
    }
  }
}

// ---- merge partials (Q>=4 only) -> Ob.  grid (12, 16): Q = bx+4 ----
__global__ __launch_bounds__(256) void k_merge(const char* __restrict__ part,
                                               bf16_t* __restrict__ Ob) {
  const int Q = blockIdx.x + 4, h = blockIdx.y;
  const int g = Q >> 2, nch = g + 1;
  const int cum = 2 * g * (g + 1) + (Q & 3) * nch - 4;
  const int t = threadIdx.x;
  const int row = t >> 1, half = t & 1;

  float acc[32];
#pragma unroll
  for (int e = 0; e < 32; ++e) acc[e] = 0.f;
  float M = -3e38f, L = 0.f;

  for (int c = 0; c < nch; ++c) {
    const char* pb = part + (size_t)(h * PART_SLOTS + cum + c) * PART_STRIDE;
    float mc = ((const float*)(pb + 16384))[row];
    float lc = ((const float*)(pb + 16896))[row];
    float Mn = fmaxf(M, mc);
    float sOld = __builtin_amdgcn_exp2f(M - Mn), sNew = __builtin_amdgcn_exp2f(mc - Mn);
    M = Mn;
    L = L * sOld + lc * sNew;
    const bf16_t* od = (const bf16_t*)pb + row * 64 + half * 32;
#pragma unroll
    for (int e4 = 0; e4 < 4; ++e4) {
      bf16x8 o8 = *reinterpret_cast<const bf16x8*>(od + e4 * 8);
#pragma unroll
      for (int e = 0; e < 8; ++e)
        acc[e4 * 8 + e] = acc[e4 * 8 + e] * sOld + (float)o8[e] * sNew;
    }
  }
  const float inv = 1.0f / L;
  bf16_t* dst = Ob + (size_t)(Q * 128 + row) * DIM + h * DH + half * 32;
#pragma unroll
  for (int e4 = 0; e4 < 4; ++e4) {
    bf16x8 r8o;
#pragma unroll
    for (int e = 0; e < 8; ++e) r8o[e] = (bf16_t)(acc[e4 * 8 + e] * inv);
    *reinterpret_cast<bf16x8*>(dst + e4 * 8) = r8o;
  }
}

// ---- host ----
extern "C" void kernel_launch(void* const* d_in, const int* in_sizes, int n_in,
                              void* d_out, int out_size, void* d_ws, size_t ws_size,
                              hipStream_t stream) {
  const float* x       = (const float*)d_in[0];
  const float* pos_sin = (const float*)d_in[1];
  const float* pos_cos = (const float*)d_in[2];
  const int*   mask    = (const int*)d_in[3];
  const float* ln_s    = (const float*)d_in[4];
  const float* ln_b    = (const float*)d_in[5];
  const float* w_qkv   = (const float*)d_in[6];
  const float* w_out   = (const float*)d_in[7];
  const float* b_out   = (const float*)d_in[8];
  float* out = (float*)d_out;

  if (ws_size < 33554432u) return;

  char* ws = (char*)d_ws;
  bf16_t* Qp   = (bf16_t*)(ws + 0);           //  4 MiB: 2048x1024
  bf16_t* Kp   = (bf16_t*)(ws + 4194304);     //  4 MiB: 16x2048x64
  bf16_t* Vt   = (bf16_t*)(ws + 8388608);     //  4 MiB: 16x64x2048
  bf16_t* Ob   = (bf16_t*)(ws + 12582912);    //  4 MiB: 2048x1024
  bf16_t* Wot  = (bf16_t*)(ws + 16777216);    //  2 MiB, alive whole run
  bf16_t* xn   = (bf16_t*)(ws + 18874368);    //  4 MiB, dead after QKV gemm
  bf16_t* Wqt  = (bf16_t*)(ws + 23068672);    //  6 MiB, dead after QKV gemm
  char*   part = ws + 18874368;               // 10.03 MiB (16*36*17408), overlays xn/Wqt

  k_ln_tc<<<NTOK + 768 + 256, 256, 0, stream>>>(x, ln_s, ln_b, xn, w_qkv, Wqt, w_out, Wot);
  k_gemm_qkv<<<dim3(16, 24), 256, 0, stream>>>(xn, Wqt, Qp, Kp, Vt, pos_sin, pos_cos);
  k_attn_part<<<16 * (SLOTS_PER_HEAD + 1), 512, 0, stream>>>(Qp, Kp, Vt, mask, part, Ob);
  k_merge<<<dim3(12, 16), 256, 0, stream>>>(part, Ob);
  k_gemm64<<<dim3(32, 16), 256, 0, stream>>>(Ob, Wot, out, b_out, NTOK, DIM, DIM);
}

// Round 17
// 85.490 us; speedup vs baseline: 3.1933x; 1.0098x over previous
//
#include <hip/hip_runtime.h>
#include <hip/hip_bf16.h>
#include <stdint.h>

typedef __bf16 bf16_t;
typedef __bf16 bf16x8 __attribute__((ext_vector_type(8)));
typedef __bf16 bf16x4 __attribute__((ext_vector_type(4)));
typedef float  f32x4  __attribute__((ext_vector_type(4)));

#define DEV __device__ __forceinline__

static constexpr int NTOK = 2048;
static constexpr int DIM  = 1024;
static constexpr int NH   = 16;
static constexpr int DH   = 64;
static constexpr int SLOTS_PER_HEAD = 40;   // sum over Q=0..15 of ceil((Q+1)/4)
static constexpr int PART_SLOTS = 36;       // slots 4..39 go through part/merge
static constexpr int PART_STRIDE = 17408;   // 128x64 bf16 (16384) + m2[128] f32 + l[128] f32
static constexpr float L2E = 1.44269504f;

// LPT dispatch order: 28 eight-tile slots, then 6-tile, 4-tile, 2-tile
__device__ static constexpr unsigned char SLOT_ORDER[40] = {
    39, 38, 37, 36, 34, 33, 32, 30, 29, 28, 26, 25, 24, 23,
    22, 21, 19, 18, 16, 15, 13, 12, 11, 10, 8, 6, 4, 3,
    35, 20, 9, 2,   // 6-tile
    31, 17, 7, 1,   // 4-tile
    27, 14, 5, 0};  // 2-tile

DEV void gload_lds16(const void* g, void* l) {
  __builtin_amdgcn_global_load_lds(
      (__attribute__((address_space(1))) void*)(g),
      (__attribute__((address_space(3))) void*)(l), 16, 0, 0);
}

DEV float bf2f(bf16_t b) { return (float)b; }

// ---- fused: LayerNorm (0..2047) + w_qkv T (2048..2815) + w_out T (2816..3071) ----
__global__ __launch_bounds__(256) void k_ln_tc(const float* __restrict__ x,
                                               const float* __restrict__ gamma,
                                               const float* __restrict__ beta,
                                               bf16_t* __restrict__ xn,
                                               const float* __restrict__ wsrc,
                                               bf16_t* __restrict__ wdst,
                                               const float* __restrict__ wosrc,
                                               bf16_t* __restrict__ wodst) {
  __shared__ float tile[64][65];
  __shared__ float red[8];
  int b = blockIdx.x;
  if (b < NTOK) {
    const int row = b;
    const int t = threadIdx.x;
    const float4* x4 = reinterpret_cast<const float4*>(x);
    float4 v = x4[(size_t)row * 256 + t];
    float s  = v.x + v.y + v.z + v.w;
    float s2 = v.x * v.x + v.y * v.y + v.z * v.z + v.w * v.w;
#pragma unroll
    for (int o = 1; o < 64; o <<= 1) {
      s  += __shfl_xor(s, o, 64);
      s2 += __shfl_xor(s2, o, 64);
    }
    const int w = t >> 6, lane = t & 63;
    if (lane == 0) { red[w] = s; red[4 + w] = s2; }
    __syncthreads();
    s  = red[0] + red[1] + red[2] + red[3];
    s2 = red[4] + red[5] + red[6] + red[7];
    const float mu  = s * (1.0f / 1024.0f);
    const float var = s2 * (1.0f / 1024.0f) - mu * mu;
    const float inv = rsqrtf(var + 1e-6f);
    const float4 g = reinterpret_cast<const float4*>(gamma)[t];
    const float4 bb = reinterpret_cast<const float4*>(beta)[t];
    bf16x4 o;
    o[0] = (bf16_t)((v.x - mu) * inv * g.x + bb.x);
    o[1] = (bf16_t)((v.y - mu) * inv * g.y + bb.y);
    o[2] = (bf16_t)((v.z - mu) * inv * g.z + bb.z);
    o[3] = (bf16_t)((v.w - mu) * inv * g.w + bb.w);
    *reinterpret_cast<bf16x4*>(xn + (size_t)row * DIM + t * 4) = o;
  } else if (b < NTOK + 768) {
    b -= NTOK;
    const int c0 = (b % 48) * 64;          // N = 3072
    const int r0 = (b / 48) * 64;          // M = 1024
    const int tx = threadIdx.x & 63;
    const int ty = threadIdx.x >> 6;
#pragma unroll
    for (int i = 0; i < 16; ++i) {
      int r = ty + i * 4;
      tile[r][tx] = wsrc[(size_t)(r0 + r) * 3072 + c0 + tx];
    }
    __syncthreads();
#pragma unroll
    for (int i = 0; i < 16; ++i) {
      int r = ty + i * 4;
      wdst[(size_t)(c0 + r) * 1024 + r0 + tx] = (bf16_t)tile[tx][r];
    }
  } else {
    b -= (NTOK + 768);
    const int c0 = (b & 15) * 64;          // N = 1024
    const int r0 = (b >> 4) * 64;          // M = 1024
    const int tx = threadIdx.x & 63;
    const int ty = threadIdx.x >> 6;
#pragma unroll
    for (int i = 0; i < 16; ++i) {
      int r = ty + i * 4;
      tile[r][tx] = wosrc[(size_t)(r0 + r) * 1024 + c0 + tx];
    }
    __syncthreads();
#pragma unroll
    for (int i = 0; i < 16; ++i) {
      int r = ty + i * 4;
      wodst[(size_t)(c0 + r) * 1024 + r0 + tx] = (bf16_t)tile[tx][r];
    }
  }
}

// ---- QKV GEMM 128x128 (m97 layout), counted-vmcnt 2-phase + fused RoPE epilogue ----
// q cols -> Qp[2048][1024] (roped, *1/32); k cols -> Kp[h][n][64] (roped); v -> Vt[h][d][n]
__global__ __launch_bounds__(256) void k_gemm_qkv(const bf16_t* __restrict__ A,
                                                  const bf16_t* __restrict__ Bt,
                                                  bf16_t* __restrict__ Qp,
                                                  bf16_t* __restrict__ Kp,
                                                  bf16_t* __restrict__ Vt,
                                                  const float* __restrict__ psin,
                                                  const float* __restrict__ pcos) {
  __shared__ alignas(16) bf16_t As[2][128 * 32];   // 2 x 8 KB
  __shared__ alignas(16) bf16_t Bs[2][128 * 32];   // 2 x 8 KB
  const int K = DIM;
  const int tid = threadIdx.x, lane = tid & 63, w = tid >> 6;
  const int bm = blockIdx.x * 128, bn = blockIdx.y * 128;
  const int wr = (w >> 1) * 64, wc = (w & 1) * 64;
  f32x4 acc[4][4];
#pragma unroll
  for (int i = 0; i < 4; ++i)
#pragma unroll
    for (int j = 0; j < 4; ++j) acc[i][j] = f32x4{0.f, 0.f, 0.f, 0.f};

  const int srow  = lane >> 2;
  const int scol8 = (lane & 3) * 8;

#define GSTAGEQ(KT, BUF)                                                              \
  {                                                                                   \
    _Pragma("unroll") for (int it = 0; it < 2; ++it) {                                \
      int seg = w * 2 + it;                                                           \
      gload_lds16(A  + (size_t)(bm + seg * 16 + srow) * K + (KT) + scol8,             \
                  (char*)As + (BUF) * 8192 + seg * 1024 + lane * 16);                 \
      gload_lds16(Bt + (size_t)(bn + seg * 16 + srow) * K + (KT) + scol8,             \
                  (char*)Bs + (BUF) * 8192 + seg * 1024 + lane * 16);                 \
    }                                                                                 \
  }

  GSTAGEQ(0, 0)
  int buf = 0;
  for (int kt = 0; kt < K; kt += 32, buf ^= 1) {
    if (kt + 32 < K) {
      GSTAGEQ(kt + 32, buf ^ 1)
      asm volatile("s_waitcnt vmcnt(4)" ::: "memory");
    } else {
      asm volatile("s_waitcnt vmcnt(0)" ::: "memory");
    }
    __builtin_amdgcn_s_barrier();
    bf16x8 af[4], bfr[4];
#pragma unroll
    for (int i = 0; i < 4; ++i) {
      int mrow = wr + i * 16 + (lane & 15);
      af[i] = *reinterpret_cast<const bf16x8*>((const char*)As + buf * 8192 + mrow * 64 +
                                               (lane >> 4) * 16);
    }
#pragma unroll
    for (int j = 0; j < 4; ++j) {
      int nrow = wc + j * 16 + (lane & 15);
      bfr[j] = *reinterpret_cast<const bf16x8*>((const char*)Bs + buf * 8192 + nrow * 64 +
                                                (lane >> 4) * 16);
    }
#pragma unroll
    for (int i = 0; i < 4; ++i)
#pragma unroll
      for (int j = 0; j < 4; ++j)
        acc[i][j] = __builtin_amdgcn_mfma_f32_16x16x32_bf16(af[i], bfr[j], acc[i][j], 0, 0, 0);
    __builtin_amdgcn_s_barrier();
  }
#undef GSTAGEQ

  if (bn >= 2048) {
    // V columns -> Vt[h][d][n]
#pragma unroll
    for (int i = 0; i < 4; ++i)
#pragma unroll
      for (int j = 0; j < 4; ++j) {
        int d = bn - 2048 + wc + j * 16 + (lane & 15);
        int n0v = bm + wr + i * 16 + (lane >> 4) * 4;
        bf16x4 v4;
#pragma unroll
        for (int r = 0; r < 4; ++r) v4[r] = (bf16_t)acc[i][j][r];
        *reinterpret_cast<bf16x4*>(Vt + (size_t)d * NTOK + n0v) = v4;
      }
  } else {
    // q/k columns: rope rows >=1 (pairs are adjacent lanes), q scaled by 1/32
#pragma unroll
    for (int i = 0; i < 4; ++i)
#pragma unroll
      for (int j = 0; j < 4; ++j) {
        int nn = bn + wc + j * 16 + (lane & 15);
        int tt = (nn & 63) >> 1;
        bool isq = nn < 1024;
#pragma unroll
        for (int r = 0; r < 4; ++r) {
          int mm = bm + wr + i * 16 + (lane >> 4) * 4 + r;
          float v = acc[i][j][r];
          float p = __shfl_xor(v, 1, 64);
          int pidx = (mm >= 1 ? mm - 1 : 0) * 32 + tt;
          float sn = psin[pidx], cs = pcos[pidx];
          float roped = (nn & 1) ? (v * cs + p * sn) : (v * cs - p * sn);
          if (mm < 1) roped = v;
          if (isq && mm >= 1) roped *= 0.03125f;
          if (isq)
            Qp[(size_t)mm * DIM + nn] = (bf16_t)roped;
          else {
            int hh = (nn - 1024) >> 6, dd = nn & 63;
            Kp[((size_t)hh * NTOK + mm) * DH + dd] = (bf16_t)roped;
          }
        }
      }
  }
}

// ---- out GEMM 64x64, counted-vmcnt 2-phase (f32 out + bias), grid (32,16) ----
__global__ __launch_bounds__(256) void k_gemm64(const bf16_t* __restrict__ A,
                                                const bf16_t* __restrict__ Bt,
                                                float* __restrict__ Cf,
                                                const float* __restrict__ bias,
                                                int M, int N, int K) {
  __shared__ alignas(16) bf16_t As[2][64 * 32];    // 2 x 4 KB
  __shared__ alignas(16) bf16_t Bs[2][64 * 32];    // 2 x 4 KB
  const int tid = threadIdx.x, lane = tid & 63, w = tid >> 6;
  const int bm = blockIdx.x * 64, bn = blockIdx.y * 64;
  const int wr = (w >> 1) * 32, wc = (w & 1) * 32;
  f32x4 acc[2][2];
#pragma unroll
  for (int i = 0; i < 2; ++i)
#pragma unroll
    for (int j = 0; j < 2; ++j) acc[i][j] = f32x4{0.f, 0.f, 0.f, 0.f};

  const int srow  = lane >> 2;
  const int scol8 = (lane & 3) * 8;

#define GSTAGE64(KT, BUF)                                                             \
  {                                                                                   \
    _Pragma("unroll") for (int it = 0; it < 2; ++it) {                                \
      int s = w * 2 + it;                                                             \
      if (s < 4)                                                                      \
        gload_lds16(A + (size_t)(bm + s * 16 + srow) * K + (KT) + scol8,              \
                    (char*)As + (BUF) * 4096 + s * 1024 + lane * 16);                 \
      else                                                                            \
        gload_lds16(Bt + (size_t)(bn + (s - 4) * 16 + srow) * K + (KT) + scol8,       \
                    (char*)Bs + (BUF) * 4096 + (s - 4) * 1024 + lane * 16);           \
    }                                                                                 \
  }

  GSTAGE64(0, 0)
  int buf = 0;
  for (int kt = 0; kt < K; kt += 32, buf ^= 1) {
    if (kt + 32 < K) {
      GSTAGE64(kt + 32, buf ^ 1)
      asm volatile("s_waitcnt vmcnt(2)" ::: "memory");
    } else {
      asm volatile("s_waitcnt vmcnt(0)" ::: "memory");
    }
    __builtin_amdgcn_s_barrier();
    bf16x8 af[2], bfr[2];
#pragma unroll
    for (int i = 0; i < 2; ++i) {
      int mrow = wr + i * 16 + (lane & 15);
      af[i] = *reinterpret_cast<const bf16x8*>((const char*)As + buf * 4096 + mrow * 64 +
                                               (lane >> 4) * 16);
    }
#pragma unroll
    for (int j = 0; j < 2; ++j) {
      int nrow = wc + j * 16 + (lane & 15);
      bfr[j] = *reinterpret_cast<const bf16x8*>((const char*)Bs + buf * 4096 + nrow * 64 +
                                                (lane >> 4) * 16);
    }
#pragma unroll
    for (int i = 0; i < 2; ++i)
#pragma unroll
      for (int j = 0; j < 2; ++j)
        acc[i][j] = __builtin_amdgcn_mfma_f32_16x16x32_bf16(af[i], bfr[j], acc[i][j], 0, 0, 0);
    __builtin_amdgcn_s_barrier();
  }
#undef GSTAGE64

#pragma unroll
  for (int i = 0; i < 2; ++i)
#pragma unroll
    for (int j = 0; j < 2; ++j)
#pragma unroll
      for (int r = 0; r < 4; ++r) {
        int mm = bm + wr + i * 16 + (lane >> 4) * 4 + r;
        int nn = bn + wc + j * 16 + (lane & 15);
        Cf[(size_t)mm * N + nn] = acc[i][j][r] + bias[nn];
      }
}

// ---- flash attention partials (8 waves x 16 q-rows, swapped-operand in-lane softmax)
//      3-buffer LDS rotation, ONE barrier per tile: vmcnt(own) -> barrier -> stage(it+2)
//      1-D LPT grid: idx = rank*16 + h; rank 0 = row-0 (first), ranks 1..40 via SLOT_ORDER ----
__global__ __launch_bounds__(512) void k_attn_part(const bf16_t* __restrict__ Qp,
                                                   const bf16_t* __restrict__ Kp,
                                                   const bf16_t* __restrict__ Vt,
                                                   const int* __restrict__ mask,
                                                   char* __restrict__ part,
                                                   bf16_t* __restrict__ Ob) {
  __shared__ alignas(16) bf16_t Ks[3][64][64];   // 24 KB
  __shared__ alignas(16) bf16_t Vs[3][64][64];   // 24 KB
  __shared__ alignas(16) float padf[512];        //  2 KB

  const int idx = blockIdx.x;
  const int h = idx & 15;
  const int rank = idx >> 4;

  if (rank == 0) {
    // ---------------- row 0: attends ALL 2048 keys, q un-roped/un-scaled ----------------
    float* qv   = padf;              // 64 f32
    float* sbuf = (float*)Ks;        // 2048 f32
    float* red  = (float*)Vs;        // 8 f32
    float* red2 = (float*)Vs + 64;   // 512 f32
    const int t = threadIdx.x, lane = t & 63, w8 = t >> 6;
    if (t < 64) qv[t] = (float)Qp[h * DH + t];
    __syncthreads();
    float sm[4];
    float lmax = -1e30f;
#pragma unroll
    for (int p = 0; p < 4; ++p) {
      int j = p * 512 + t;
      const bf16_t* kr = Kp + ((size_t)h * NTOK + j) * DH;
      float s = 0.f;
#pragma unroll
      for (int u = 0; u < 8; ++u) {
        bf16x8 kv8 = *reinterpret_cast<const bf16x8*>(kr + u * 8);
#pragma unroll
        for (int e = 0; e < 8; ++e) s += qv[u * 8 + e] * (float)kv8[e];
      }
      bool padj = (j == 0) || (mask[j - 1] != 0);
      s = padj ? s * 0.03125f : -1e30f;
      sm[p] = s;
      lmax = fmaxf(lmax, s);
    }
#pragma unroll
    for (int o = 1; o < 64; o <<= 1) lmax = fmaxf(lmax, __shfl_xor(lmax, o, 64));
    if (lane == 0) red[w8] = lmax;
    __syncthreads();
    float M = red[0];
#pragma unroll
    for (int i = 1; i < 8; ++i) M = fmaxf(M, red[i]);
    __syncthreads();
    float ls = 0.f;
#pragma unroll
    for (int p = 0; p < 4; ++p) {
      float pe = __expf(sm[p] - M);
      sbuf[p * 512 + t] = pe;
      ls += pe;
    }
#pragma unroll
    for (int o = 1; o < 64; o <<= 1) ls += __shfl_xor(ls, o, 64);
    if (lane == 0) red[w8] = ls;
    __syncthreads();
    float L = red[0];
#pragma unroll
    for (int i = 1; i < 8; ++i) L += red[i];

    const int d = t & 63, qr = t >> 6;
    const bf16_t* vr = Vt + ((size_t)h * DH + d) * NTOK + qr * 256;
    float a = 0.f;
#pragma unroll 8
    for (int u = 0; u < 32; ++u) {
      bf16x8 v8 = *reinterpret_cast<const bf16x8*>(vr + u * 8);
#pragma unroll
      for (int e = 0; e < 8; ++e) a += sbuf[qr * 256 + u * 8 + e] * (float)v8[e];
    }
    red2[qr * 64 + d] = a;
    __syncthreads();
    if (t < 64) {
      float o = 0.f;
#pragma unroll
      for (int i = 0; i < 8; ++i) o += red2[i * 64 + t];
      Ob[h * DH + t] = (bf16_t)(o / L);
    }
    return;
  }

  const int slot = SLOT_ORDER[rank - 1];
  int gq;
  if (slot < 4) gq = 0; else if (slot < 12) gq = 1; else if (slot < 24) gq = 2; else gq = 3;
  const int tt = slot - 2 * gq * (gq + 1);
  const int Q = (gq << 2) + tt / (gq + 1);
  const int c2 = tt - (tt / (gq + 1)) * (gq + 1);
  const int q0 = Q * 128;
  const int kbeg = c2 * 512;
  const int kvlen = (Q + 1) * 128;
  const int klen = min(512, kvlen - kbeg);
  const int ntiles = klen >> 6;                 // 2,4,6,8
  const int nch = gq + 1;

  const int tid = threadIdx.x, lane = tid & 63, w = tid >> 6;
  const int g = lane >> 4;       // lane group
  const int c = lane & 15;       // q column

  for (int jr = tid; jr < klen; jr += 512) {
    int j = kbeg + jr;
    padf[jr] = (j == 0 || mask[j - 1] != 0) ? 1.f : 0.f;
  }

  const int iw = q0 + w * 16;
  bf16x8 qf[2];
  {
    const bf16_t* qp = Qp + (size_t)(iw + c) * DIM + h * DH + g * 8;
    qf[0] = *reinterpret_cast<const bf16x8*>(qp);
    qf[1] = *reinterpret_cast<const bf16x8*>(qp + 32);
  }
  bf16x8 ones;
#pragma unroll
  for (int e = 0; e < 8; ++e) ones[e] = (bf16_t)1.0f;

  float m_run = -1e30f, m2 = -1e30f;
  f32x4 acc[4], accl;
#pragma unroll
  for (int df = 0; df < 4; ++df) acc[df] = f32x4{0.f, 0.f, 0.f, 0.f};
  accl = f32x4{0.f, 0.f, 0.f, 0.f};

  const int r8 = lane >> 3;

#define STAGE(KB, BUF)                                                                   \
  {                                                                                      \
    _Pragma("unroll") for (int i2 = 0; i2 < 2; ++i2) {                                   \
      int s = w * 2 + i2;                                                                \
      int sw = (lane & 7) ^ r8 ^ ((s & 3) << 1);                                         \
      if (s < 8) {                                                                       \
        int row = s * 8 + r8;                                                            \
        gload_lds16(Kp + ((size_t)h * NTOK + (KB) + row) * DH + sw * 8,                  \
                    (char*)Ks + (BUF)*8192 + s * 1024 + lane * 16);                      \
      } else {                                                                           \
        int row = (s - 8) * 8 + r8;                                                      \
        gload_lds16(Vt + ((size_t)h * DH + row) * NTOK + (KB) + sw * 8,                  \
                    (char*)Vs + (BUF)*8192 + (s - 8) * 1024 + lane * 16);                \
      }                                                                                  \
    }                                                                                    \
  }

  // prologue: buffers 0 and 1 (ntiles >= 2 always)
  STAGE(kbeg, 0)
  STAGE(kbeg + 64, 1)

  int buf = 0;
  for (int it = 0; it < ntiles; ++it) {
    // own oldest loads (buffer `buf`, issued 2 iters ago) must have landed
    if (it == ntiles - 1) {
      asm volatile("s_waitcnt vmcnt(0)" ::: "memory");
    } else {
      asm volatile("s_waitcnt vmcnt(2)" ::: "memory");
    }
    __builtin_amdgcn_s_barrier();   // all waves' loads for `buf` landed; prev compute done
    if (it + 2 < ntiles) {
      int nbuf = buf + 2;
      if (nbuf >= 3) nbuf -= 3;
      STAGE(kbeg + (it + 2) * 64, nbuf)
    }

    const int k0 = kbeg + it * 64;
    if (k0 <= iw + 15) {
      const char* KsT = (const char*)Ks + buf * 8192;
      const char* VsT = (const char*)Vs + buf * 8192;

      f32x4 sfr[4];
      __builtin_amdgcn_s_setprio(1);
#pragma unroll
      for (int f = 0; f < 4; ++f) {
        int key7 = ((f & 1) * 4) | (c & 3);
        int key = (f >> 1) * 32 + (c >> 2) * 8 + key7;
        int phi = key7 ^ (((c >> 2) & 3) << 1);
        f32x4 s = f32x4{0.f, 0.f, 0.f, 0.f};
#pragma unroll
        for (int kd = 0; kd < 2; ++kd) {
          bf16x8 kf = *reinterpret_cast<const bf16x8*>(
              KsT + key * 128 + (((kd * 4 + g) ^ phi) << 4));
          s = __builtin_amdgcn_mfma_f32_16x16x32_bf16(kf, qf[kd], s, 0, 0, 0);
        }
        sfr[f] = s;
      }
      __builtin_amdgcn_s_setprio(0);

      float pm = fmaxf(fmaxf(sfr[0][0], sfr[0][1]), fmaxf(sfr[0][2], sfr[0][3]));
#pragma unroll
      for (int f = 1; f < 4; ++f)
        pm = fmaxf(pm, fmaxf(fmaxf(sfr[f][0], sfr[f][1]), fmaxf(sfr[f][2], sfr[f][3])));
      pm = fmaxf(pm, __shfl_xor(pm, 16, 64));
      pm = fmaxf(pm, __shfl_xor(pm, 32, 64));

      if (!__all(pm <= m_run + 8.f)) {
        float mnew = fmaxf(m_run, pm);
        float corr = __builtin_amdgcn_exp2f((m_run - mnew) * L2E);
        m_run = mnew;
        m2 = mnew * L2E;
#pragma unroll
        for (int r = 0; r < 4; ++r) {
          float cr = __shfl(corr, g * 4 + r, 64);
          accl[r] *= cr;
#pragma unroll
          for (int df = 0; df < 4; ++df) acc[df][r] *= cr;
        }
      }

      const bool needC = (k0 + 63 > iw);
      const int qlane = iw + c;
      bf16x8 pa[2];
#pragma unroll
      for (int f = 0; f < 4; ++f) {
        int jb = (k0 - kbeg) + (f >> 1) * 32 + g * 8 + (f & 1) * 4;
        f32x4 pad4 = *reinterpret_cast<const f32x4*>(padf + jb);
#pragma unroll
        for (int r = 0; r < 4; ++r) {
          float pe = __builtin_amdgcn_exp2f(__builtin_fmaf(sfr[f][r], L2E, -m2)) * pad4[r];
          if (needC) pe = (kbeg + jb + r <= qlane) ? pe : 0.f;
          pa[f >> 1][(f & 1) * 4 + r] = (bf16_t)pe;
        }
      }

      __builtin_amdgcn_s_setprio(1);
#pragma unroll
      for (int ks = 0; ks < 2; ++ks) {
        accl = __builtin_amdgcn_mfma_f32_16x16x32_bf16(pa[ks], ones, accl, 0, 0, 0);
#pragma unroll
        for (int df = 0; df < 4; ++df) {
          int d = df * 16 + c;
          int phv = (d & 7) ^ (((d >> 3) & 3) << 1);
          bf16x8 vf = *reinterpret_cast<const bf16x8*>(
              VsT + d * 128 + (((ks * 4 + g) ^ phv) << 4));
          acc[df] = __builtin_amdgcn_mfma_f32_16x16x32_bf16(pa[ks], vf, acc[df], 0, 0, 0);
        }
      }
      __builtin_amdgcn_s_setprio(0);
    }

    ++buf;
    if (buf == 3) buf = 0;
  }
#undef STAGE

  if (nch == 1) {
    // single-chunk Q (Q<4): normalize and write Ob directly; row 0 owned by row-0 path
#pragma unroll
    for (int r = 0; r < 4; ++r) {
      float inv = 1.0f / accl[r];
      int row = w * 16 + g * 4 + r;
#pragma unroll
      for (int df = 0; df < 4; ++df) {
        if (q0 + row != 0)
          Ob[(size_t)(q0 + row) * DIM + h * DH + df * 16 + c] = (bf16_t)(acc[df][r] * inv);
      }
    }
    return;
  }

  // write unnormalized partial (merged by separate k_merge kernel)
  char* pb = part + (size_t)(h * PART_SLOTS + (slot - 4)) * PART_STRIDE;
  bf16_t* po = (bf16_t*)pb;
  float* pmo = (float*)(pb + 16384);
  float* plo = (float*)(pb + 16896);
  float mq[4];
#pragma unroll
  for (int r = 0; r < 4; ++r) mq[r] = __shfl(m2, g * 4 + r, 64);
#pragma unroll
  for (int df = 0; df < 4; ++df)
#pragma unroll
    for (int r = 0; r < 4; ++r) {
      int row = w * 16 + g * 4 + r;
      po[row * 64 + df * 16 + c] = (bf16_t)acc[df][r];
    }
  if (c == 0) {
#pragma unroll
    for (int r = 0; r < 4; ++r) {
      int row = w * 16 + g * 4 + r;
      pmo[row] = mq[r];      // log2 units
      plo[row] = accl[r];
    }
  }
}

// ---- merge partials (Q>=4 only) -> Ob.  grid (12, 16): Q = bx+4 ----
__global__ __launch_bounds__(256) void k_merge(const char* __restrict__ part,
                                               bf16_t* __restrict__ Ob) {
  const int Q = blockIdx.x + 4, h = blockIdx.y;
  const int g = Q >> 2, nch = g + 1;
  const int cum = 2 * g * (g + 1) + (Q & 3) * nch - 4;
  const int t = threadIdx.x;
  const int row = t >> 1, half = t & 1;

  float acc[32];
#pragma unroll
  for (int e = 0; e < 32; ++e) acc[e] = 0.f;
  float M = -3e38f, L = 0.f;

  for (int c = 0; c < nch; ++c) {
    const char* pb = part + (size_t)(h * PART_SLOTS + cum + c) * PART_STRIDE;
    float mc = ((const float*)(pb + 16384))[row];
    float lc = ((const float*)(pb + 16896))[row];
    float Mn = fmaxf(M, mc);
    float sOld = __builtin_amdgcn_exp2f(M - Mn), sNew = __builtin_amdgcn_exp2f(mc - Mn);
    M = Mn;
    L = L * sOld + lc * sNew;
    const bf16_t* od = (const bf16_t*)pb + row * 64 + half * 32;
#pragma unroll
    for (int e4 = 0; e4 < 4; ++e4) {
      bf16x8 o8 = *reinterpret_cast<const bf16x8*>(od + e4 * 8);
#pragma unroll
      for (int e = 0; e < 8; ++e)
        acc[e4 * 8 + e] = acc[e4 * 8 + e] * sOld + (float)o8[e] * sNew;
    }
  }
  const float inv = 1.0f / L;
  bf16_t* dst = Ob + (size_t)(Q * 128 + row) * DIM + h * DH + half * 32;
#pragma unroll
  for (int e4 = 0; e4 < 4; ++e4) {
    bf16x8 r8o;
#pragma unroll
    for (int e = 0; e < 8; ++e) r8o[e] = (bf16_t)(acc[e4 * 8 + e] * inv);
    *reinterpret_cast<bf16x8*>(dst + e4 * 8) = r8o;
  }
}

// ---- host ----
extern "C" void kernel_launch(void* const* d_in, const int* in_sizes, int n_in,
                              void* d_out, int out_size, void* d_ws, size_t ws_size,
                              hipStream_t stream) {
  const float* x       = (const float*)d_in[0];
  const float* pos_sin = (const float*)d_in[1];
  const float* pos_cos = (const float*)d_in[2];
  const int*   mask    = (const int*)d_in[3];
  const float* ln_s    = (const float*)d_in[4];
  const float* ln_b    = (const float*)d_in[5];
  const float* w_qkv   = (const float*)d_in[6];
  const float* w_out   = (const float*)d_in[7];
  const float* b_out   = (const float*)d_in[8];
  float* out = (float*)d_out;

  if (ws_size < 33554432u) return;

  char* ws = (char*)d_ws;
  bf16_t* Qp   = (bf16_t*)(ws + 0);           //  4 MiB: 2048x1024
  bf16_t* Kp   = (bf16_t*)(ws + 4194304);     //  4 MiB: 16x2048x64
  bf16_t* Vt   = (bf16_t*)(ws + 8388608);     //  4 MiB: 16x64x2048
  bf16_t* Ob   = (bf16_t*)(ws + 12582912);    //  4 MiB: 2048x1024
  bf16_t* Wot  = (bf16_t*)(ws + 16777216);    //  2 MiB, alive whole run
  bf16_t* xn   = (bf16_t*)(ws + 18874368);    //  4 MiB, dead after QKV gemm
  bf16_t* Wqt  = (bf16_t*)(ws + 23068672);    //  6 MiB, dead after QKV gemm
  char*   part = ws + 18874368;               // 10.03 MiB (16*36*17408), overlays xn/Wqt

  k_ln_tc<<<NTOK + 768 + 256, 256, 0, stream>>>(x, ln_s, ln_b, xn, w_qkv, Wqt, w_out, Wot);
  k_gemm_qkv<<<dim3(16, 24), 256, 0, stream>>>(xn, Wqt, Qp, Kp, Vt, pos_sin, pos_cos);
  k_attn_part<<<16 * (SLOTS_PER_HEAD + 1), 512, 0, stream>>>(Qp, Kp, Vt, mask, part, Ob);
  k_merge<<<dim3(12, 16), 256, 0, stream>>>(part, Ob);
  k_gemm64<<<dim3(32, 16), 256, 0, stream>>>(Ob, Wot, out, b_out, NTOK, DIM, DIM);
}

// Round 18
// 85.162 us; speedup vs baseline: 3.2056x; 1.0039x over previous
//
#include <hip/hip_runtime.h>
#include <hip/hip_bf16.h>
#include <stdint.h>

typedef __bf16 bf16_t;
typedef __bf16 bf16x8 __attribute__((ext_vector_type(8)));
typedef __bf16 bf16x4 __attribute__((ext_vector_type(4)));
typedef float  f32x4  __attribute__((ext_vector_type(4)));

#define DEV __device__ __forceinline__

static constexpr int NTOK = 2048;
static constexpr int DIM  = 1024;
static constexpr int NH   = 16;
static constexpr int DH   = 64;
static constexpr int SLOTS_PER_HEAD = 40;   // sum over Q=0..15 of ceil((Q+1)/4)
static constexpr int PART_SLOTS = 36;       // slots 4..39 go through part/merge
static constexpr int PART_STRIDE = 17408;   // 128x64 bf16 (16384) + m2[128] f32 + l[128] f32
static constexpr float L2E = 1.44269504f;

// LPT dispatch order: 28 eight-tile slots, then 6-tile, 4-tile, 2-tile
__device__ static constexpr unsigned char SLOT_ORDER[40] = {
    39, 38, 37, 36, 34, 33, 32, 30, 29, 28, 26, 25, 24, 23,
    22, 21, 19, 18, 16, 15, 13, 12, 11, 10, 8, 6, 4, 3,
    35, 20, 9, 2,   // 6-tile
    31, 17, 7, 1,   // 4-tile
    27, 14, 5, 0};  // 2-tile

DEV void gload_lds16(const void* g, void* l) {
  __builtin_amdgcn_global_load_lds(
      (__attribute__((address_space(1))) void*)(g),
      (__attribute__((address_space(3))) void*)(l), 16, 0, 0);
}

DEV float bf2f(bf16_t b) { return (float)b; }

// ---- fused: LayerNorm (0..2047) + w_qkv T (2048..2815) + w_out T (2816..3071) ----
__global__ __launch_bounds__(256) void k_ln_tc(const float* __restrict__ x,
                                               const float* __restrict__ gamma,
                                               const float* __restrict__ beta,
                                               bf16_t* __restrict__ xn,
                                               const float* __restrict__ wsrc,
                                               bf16_t* __restrict__ wdst,
                                               const float* __restrict__ wosrc,
                                               bf16_t* __restrict__ wodst) {
  __shared__ float tile[64][65];
  __shared__ float red[8];
  int b = blockIdx.x;
  if (b < NTOK) {
    const int row = b;
    const int t = threadIdx.x;
    const float4* x4 = reinterpret_cast<const float4*>(x);
    float4 v = x4[(size_t)row * 256 + t];
    float s  = v.x + v.y + v.z + v.w;
    float s2 = v.x * v.x + v.y * v.y + v.z * v.z + v.w * v.w;
#pragma unroll
    for (int o = 1; o < 64; o <<= 1) {
      s  += __shfl_xor(s, o, 64);
      s2 += __shfl_xor(s2, o, 64);
    }
    const int w = t >> 6, lane = t & 63;
    if (lane == 0) { red[w] = s; red[4 + w] = s2; }
    __syncthreads();
    s  = red[0] + red[1] + red[2] + red[3];
    s2 = red[4] + red[5] + red[6] + red[7];
    const float mu  = s * (1.0f / 1024.0f);
    const float var = s2 * (1.0f / 1024.0f) - mu * mu;
    const float inv = rsqrtf(var + 1e-6f);
    const float4 g = reinterpret_cast<const float4*>(gamma)[t];
    const float4 bb = reinterpret_cast<const float4*>(beta)[t];
    bf16x4 o;
    o[0] = (bf16_t)((v.x - mu) * inv * g.x + bb.x);
    o[1] = (bf16_t)((v.y - mu) * inv * g.y + bb.y);
    o[2] = (bf16_t)((v.z - mu) * inv * g.z + bb.z);
    o[3] = (bf16_t)((v.w - mu) * inv * g.w + bb.w);
    *reinterpret_cast<bf16x4*>(xn + (size_t)row * DIM + t * 4) = o;
  } else if (b < NTOK + 768) {
    b -= NTOK;
    const int c0 = (b % 48) * 64;          // N = 3072
    const int r0 = (b / 48) * 64;          // M = 1024
    const int tx = threadIdx.x & 63;
    const int ty = threadIdx.x >> 6;
#pragma unroll
    for (int i = 0; i < 16; ++i) {
      int r = ty + i * 4;
      tile[r][tx] = wsrc[(size_t)(r0 + r) * 3072 + c0 + tx];
    }
    __syncthreads();
#pragma unroll
    for (int i = 0; i < 16; ++i) {
      int r = ty + i * 4;
      wdst[(size_t)(c0 + r) * 1024 + r0 + tx] = (bf16_t)tile[tx][r];
    }
  } else {
    b -= (NTOK + 768);
    const int c0 = (b & 15) * 64;          // N = 1024
    const int r0 = (b >> 4) * 64;          // M = 1024
    const int tx = threadIdx.x & 63;
    const int ty = threadIdx.x >> 6;
#pragma unroll
    for (int i = 0; i < 16; ++i) {
      int r = ty + i * 4;
      tile[r][tx] = wosrc[(size_t)(r0 + r) * 1024 + c0 + tx];
    }
    __syncthreads();
#pragma unroll
    for (int i = 0; i < 16; ++i) {
      int r = ty + i * 4;
      wodst[(size_t)(c0 + r) * 1024 + r0 + tx] = (bf16_t)tile[tx][r];
    }
  }
}

// ---- QKV GEMM 128x128 (m97 layout), counted-vmcnt 2-phase + fused RoPE epilogue ----
// q cols -> Qp[2048][1024] (roped, *1/32); k cols -> Kp[h][n][64] (roped); v -> Vt[h][d][n]
__global__ __launch_bounds__(256) void k_gemm_qkv(const bf16_t* __restrict__ A,
                                                  const bf16_t* __restrict__ Bt,
                                                  bf16_t* __restrict__ Qp,
                                                  bf16_t* __restrict__ Kp,
                                                  bf16_t* __restrict__ Vt,
                                                  const float* __restrict__ psin,
                                                  const float* __restrict__ pcos) {
  __shared__ alignas(16) bf16_t As[2][128 * 32];   // 2 x 8 KB
  __shared__ alignas(16) bf16_t Bs[2][128 * 32];   // 2 x 8 KB
  const int K = DIM;
  const int tid = threadIdx.x, lane = tid & 63, w = tid >> 6;
  const int bm = blockIdx.x * 128, bn = blockIdx.y * 128;
  const int wr = (w >> 1) * 64, wc = (w & 1) * 64;
  f32x4 acc[4][4];
#pragma unroll
  for (int i = 0; i < 4; ++i)
#pragma unroll
    for (int j = 0; j < 4; ++j) acc[i][j] = f32x4{0.f, 0.f, 0.f, 0.f};

  const int srow  = lane >> 2;
  const int scol8 = (lane & 3) * 8;

#define GSTAGEQ(KT, BUF)                                                              \
  {                                                                                   \
    _Pragma("unroll") for (int it = 0; it < 2; ++it) {                                \
      int seg = w * 2 + it;                                                           \
      gload_lds16(A  + (size_t)(bm + seg * 16 + srow) * K + (KT) + scol8,             \
                  (char*)As + (BUF) * 8192 + seg * 1024 + lane * 16);                 \
      gload_lds16(Bt + (size_t)(bn + seg * 16 + srow) * K + (KT) + scol8,             \
                  (char*)Bs + (BUF) * 8192 + seg * 1024 + lane * 16);                 \
    }                                                                                 \
  }

  GSTAGEQ(0, 0)
  int buf = 0;
  for (int kt = 0; kt < K; kt += 32, buf ^= 1) {
    if (kt + 32 < K) {
      GSTAGEQ(kt + 32, buf ^ 1)
      asm volatile("s_waitcnt vmcnt(4)" ::: "memory");
    } else {
      asm volatile("s_waitcnt vmcnt(0)" ::: "memory");
    }
    __builtin_amdgcn_s_barrier();
    bf16x8 af[4], bfr[4];
#pragma unroll
    for (int i = 0; i < 4; ++i) {
      int mrow = wr + i * 16 + (lane & 15);
      af[i] = *reinterpret_cast<const bf16x8*>((const char*)As + buf * 8192 + mrow * 64 +
                                               (lane >> 4) * 16);
    }
#pragma unroll
    for (int j = 0; j < 4; ++j) {
      int nrow = wc + j * 16 + (lane & 15);
      bfr[j] = *reinterpret_cast<const bf16x8*>((const char*)Bs + buf * 8192 + nrow * 64 +
                                                (lane >> 4) * 16);
    }
#pragma unroll
    for (int i = 0; i < 4; ++i)
#pragma unroll
      for (int j = 0; j < 4; ++j)
        acc[i][j] = __builtin_amdgcn_mfma_f32_16x16x32_bf16(af[i], bfr[j], acc[i][j], 0, 0, 0);
    __builtin_amdgcn_s_barrier();
  }
#undef GSTAGEQ

  if (bn >= 2048) {
    // V columns -> Vt[h][d][n]
#pragma unroll
    for (int i = 0; i < 4; ++i)
#pragma unroll
      for (int j = 0; j < 4; ++j) {
        int d = bn - 2048 + wc + j * 16 + (lane & 15);
        int n0v = bm + wr + i * 16 + (lane >> 4) * 4;
        bf16x4 v4;
#pragma unroll
        for (int r = 0; r < 4; ++r) v4[r] = (bf16_t)acc[i][j][r];
        *reinterpret_cast<bf16x4*>(Vt + (size_t)d * NTOK + n0v) = v4;
      }
  } else {
    // q/k columns: rope rows >=1 (pairs are adjacent lanes), q scaled by 1/32
#pragma unroll
    for (int i = 0; i < 4; ++i)
#pragma unroll
      for (int j = 0; j < 4; ++j) {
        int nn = bn + wc + j * 16 + (lane & 15);
        int tt = (nn & 63) >> 1;
        bool isq = nn < 1024;
#pragma unroll
        for (int r = 0; r < 4; ++r) {
          int mm = bm + wr + i * 16 + (lane >> 4) * 4 + r;
          float v = acc[i][j][r];
          float p = __shfl_xor(v, 1, 64);
          int pidx = (mm >= 1 ? mm - 1 : 0) * 32 + tt;
          float sn = psin[pidx], cs = pcos[pidx];
          float roped = (nn & 1) ? (v * cs + p * sn) : (v * cs - p * sn);
          if (mm < 1) roped = v;
          if (isq && mm >= 1) roped *= 0.03125f;
          if (isq)
            Qp[(size_t)mm * DIM + nn] = (bf16_t)roped;
          else {
            int hh = (nn - 1024) >> 6, dd = nn & 63;
            Kp[((size_t)hh * NTOK + mm) * DH + dd] = (bf16_t)roped;
          }
        }
      }
  }
}

// ---- out GEMM 64x64, counted-vmcnt 2-phase (f32 out + bias), grid (32,16) ----
__global__ __launch_bounds__(256) void k_gemm64(const bf16_t* __restrict__ A,
                                                const bf16_t* __restrict__ Bt,
                                                float* __restrict__ Cf,
                                                const float* __restrict__ bias,
                                                int M, int N, int K) {
  __shared__ alignas(16) bf16_t As[2][64 * 32];    // 2 x 4 KB
  __shared__ alignas(16) bf16_t Bs[2][64 * 32];    // 2 x 4 KB
  const int tid = threadIdx.x, lane = tid & 63, w = tid >> 6;
  const int bm = blockIdx.x * 64, bn = blockIdx.y * 64;
  const int wr = (w >> 1) * 32, wc = (w & 1) * 32;
  f32x4 acc[2][2];
#pragma unroll
  for (int i = 0; i < 2; ++i)
#pragma unroll
    for (int j = 0; j < 2; ++j) acc[i][j] = f32x4{0.f, 0.f, 0.f, 0.f};

  const int srow  = lane >> 2;
  const int scol8 = (lane & 3) * 8;

#define GSTAGE64(KT, BUF)                                                             \
  {                                                                                   \
    _Pragma("unroll") for (int it = 0; it < 2; ++it) {                                \
      int s = w * 2 + it;                                                             \
      if (s < 4)                                                                      \
        gload_lds16(A + (size_t)(bm + s * 16 + srow) * K + (KT) + scol8,              \
                    (char*)As + (BUF) * 4096 + s * 1024 + lane * 16);                 \
      else                                                                            \
        gload_lds16(Bt + (size_t)(bn + (s - 4) * 16 + srow) * K + (KT) + scol8,       \
                    (char*)Bs + (BUF) * 4096 + (s - 4) * 1024 + lane * 16);           \
    }                                                                                 \
  }

  GSTAGE64(0, 0)
  int buf = 0;
  for (int kt = 0; kt < K; kt += 32, buf ^= 1) {
    if (kt + 32 < K) {
      GSTAGE64(kt + 32, buf ^ 1)
      asm volatile("s_waitcnt vmcnt(2)" ::: "memory");
    } else {
      asm volatile("s_waitcnt vmcnt(0)" ::: "memory");
    }
    __builtin_amdgcn_s_barrier();
    bf16x8 af[2], bfr[2];
#pragma unroll
    for (int i = 0; i < 2; ++i) {
      int mrow = wr + i * 16 + (lane & 15);
      af[i] = *reinterpret_cast<const bf16x8*>((const char*)As + buf * 4096 + mrow * 64 +
                                               (lane >> 4) * 16);
    }
#pragma unroll
    for (int j = 0; j < 2; ++j) {
      int nrow = wc + j * 16 + (lane & 15);
      bfr[j] = *reinterpret_cast<const bf16x8*>((const char*)Bs + buf * 4096 + nrow * 64 +
                                                (lane >> 4) * 16);
    }
#pragma unroll
    for (int i = 0; i < 2; ++i)
#pragma unroll
      for (int j = 0; j < 2; ++j)
        acc[i][j] = __builtin_amdgcn_mfma_f32_16x16x32_bf16(af[i], bfr[j], acc[i][j], 0, 0, 0);
    __builtin_amdgcn_s_barrier();
  }
#undef GSTAGE64

#pragma unroll
  for (int i = 0; i < 2; ++i)
#pragma unroll
    for (int j = 0; j < 2; ++j)
#pragma unroll
      for (int r = 0; r < 4; ++r) {
        int mm = bm + wr + i * 16 + (lane >> 4) * 4 + r;
        int nn = bn + wc + j * 16 + (lane & 15);
        Cf[(size_t)mm * N + nn] = acc[i][j][r] + bias[nn];
      }
}

// ---- flash attention partials (8 waves x 16 q-rows, swapped-operand in-lane softmax)
//      3-buffer LDS rotation, ONE barrier per tile: vmcnt(own) -> barrier -> stage(it+2)
//      1-D LPT grid: idx = rank*16 + h; rank 0 = row-0 (first), ranks 1..40 via SLOT_ORDER ----
__global__ __launch_bounds__(512) void k_attn_part(const bf16_t* __restrict__ Qp,
                                                   const bf16_t* __restrict__ Kp,
                                                   const bf16_t* __restrict__ Vt,
                                                   const int* __restrict__ mask,
                                                   char* __restrict__ part,
                                                   bf16_t* __restrict__ Ob) {
  __shared__ alignas(16) bf16_t Ks[3][64][64];   // 24 KB
  __shared__ alignas(16) bf16_t Vs[3][64][64];   // 24 KB
  __shared__ alignas(16) float padf[512];        //  2 KB

  const int idx = blockIdx.x;
  const int h = idx & 15;
  const int rank = idx >> 4;

  if (rank == 0) {
    // ---------------- row 0: attends ALL 2048 keys, q un-roped/un-scaled ----------------
    float* qv   = padf;              // 64 f32
    float* sbuf = (float*)Ks;        // 2048 f32
    float* red  = (float*)Vs;        // 8 f32
    float* red2 = (float*)Vs + 64;   // 512 f32
    const int t = threadIdx.x, lane = t & 63, w8 = t >> 6;
    if (t < 64) qv[t] = (float)Qp[h * DH + t];
    __syncthreads();
    float sm[4];
    float lmax = -1e30f;
#pragma unroll
    for (int p = 0; p < 4; ++p) {
      int j = p * 512 + t;
      const bf16_t* kr = Kp + ((size_t)h * NTOK + j) * DH;
      float s = 0.f;
#pragma unroll
      for (int u = 0; u < 8; ++u) {
        bf16x8 kv8 = *reinterpret_cast<const bf16x8*>(kr + u * 8);
#pragma unroll
        for (int e = 0; e < 8; ++e) s += qv[u * 8 + e] * (float)kv8[e];
      }
      bool padj = (j == 0) || (mask[j - 1] != 0);
      s = padj ? s * 0.03125f : -1e30f;
      sm[p] = s;
      lmax = fmaxf(lmax, s);
    }
#pragma unroll
    for (int o = 1; o < 64; o <<= 1) lmax = fmaxf(lmax, __shfl_xor(lmax, o, 64));
    if (lane == 0) red[w8] = lmax;
    __syncthreads();
    float M = red[0];
#pragma unroll
    for (int i = 1; i < 8; ++i) M = fmaxf(M, red[i]);
    __syncthreads();
    float ls = 0.f;
#pragma unroll
    for (int p = 0; p < 4; ++p) {
      float pe = __expf(sm[p] - M);
      sbuf[p * 512 + t] = pe;
      ls += pe;
    }
#pragma unroll
    for (int o = 1; o < 64; o <<= 1) ls += __shfl_xor(ls, o, 64);
    if (lane == 0) red[w8] = ls;
    __syncthreads();
    float L = red[0];
#pragma unroll
    for (int i = 1; i < 8; ++i) L += red[i];

    const int d = t & 63, qr = t >> 6;
    const bf16_t* vr = Vt + ((size_t)h * DH + d) * NTOK + qr * 256;
    float a = 0.f;
#pragma unroll 8
    for (int u = 0; u < 32; ++u) {
      bf16x8 v8 = *reinterpret_cast<const bf16x8*>(vr + u * 8);
#pragma unroll
      for (int e = 0; e < 8; ++e) a += sbuf[qr * 256 + u * 8 + e] * (float)v8[e];
    }
    red2[qr * 64 + d] = a;
    __syncthreads();
    if (t < 64) {
      float o = 0.f;
#pragma unroll
      for (int i = 0; i < 8; ++i) o += red2[i * 64 + t];
      Ob[h * DH + t] = (bf16_t)(o / L);
    }
    return;
  }

  const int slot = SLOT_ORDER[rank - 1];
  int gq;
  if (slot < 4) gq = 0; else if (slot < 12) gq = 1; else if (slot < 24) gq = 2; else gq = 3;
  const int tt = slot - 2 * gq * (gq + 1);
  const int Q = (gq << 2) + tt / (gq + 1);
  const int c2 = tt - (tt / (gq + 1)) * (gq + 1);
  const int q0 = Q * 128;
  const int kbeg = c2 * 512;
  const int kvlen = (Q + 1) * 128;
  const int klen = min(512, kvlen - kbeg);
  const int ntiles = klen >> 6;                 // 2,4,6,8
  const int nch = gq + 1;

  const int tid = threadIdx.x, lane = tid & 63, w = tid >> 6;
  const int g = lane >> 4;       // lane group
  const int c = lane & 15;       // q column

  for (int jr = tid; jr < klen; jr += 512) {
    int j = kbeg + jr;
    padf[jr] = (j == 0 || mask[j - 1] != 0) ? 1.f : 0.f;
  }

  const int iw = q0 + w * 16;
  bf16x8 qf[2];
  {
    const bf16_t* qp = Qp + (size_t)(iw + c) * DIM + h * DH + g * 8;
    qf[0] = *reinterpret_cast<const bf16x8*>(qp);
    qf[1] = *reinterpret_cast<const bf16x8*>(qp + 32);
  }
  bf16x8 ones;
#pragma unroll
  for (int e = 0; e < 8; ++e) ones[e] = (bf16_t)1.0f;

  float m_run = -1e30f, m2 = -1e30f;
  f32x4 acc[4], accl;
#pragma unroll
  for (int df = 0; df < 4; ++df) acc[df] = f32x4{0.f, 0.f, 0.f, 0.f};
  accl = f32x4{0.f, 0.f, 0.f, 0.f};

  const int r8 = lane >> 3;

#define STAGE(KB, BUF)                                                                   \
  {                                                                                      \
    _Pragma("unroll") for (int i2 = 0; i2 < 2; ++i2) {                                   \
      int s = w * 2 + i2;                                                                \
      int sw = (lane & 7) ^ r8 ^ ((s & 3) << 1);                                         \
      if (s < 8) {                                                                       \
        int row = s * 8 + r8;                                                            \
        gload_lds16(Kp + ((size_t)h * NTOK + (KB) + row) * DH + sw * 8,                  \
                    (char*)Ks + (BUF)*8192 + s * 1024 + lane * 16);                      \
      } else {                                                                           \
        int row = (s - 8) * 8 + r8;                                                      \
        gload_lds16(Vt + ((size_t)h * DH + row) * NTOK + (KB) + sw * 8,                  \
                    (char*)Vs + (BUF)*8192 + (s - 8) * 1024 + lane * 16);                \
      }                                                                                  \
    }                                                                                    \
  }

  // prologue: buffers 0 and 1 (ntiles >= 2 always)
  STAGE(kbeg, 0)
  STAGE(kbeg + 64, 1)

  int buf = 0;
  for (int it = 0; it < ntiles; ++it) {
    // own oldest loads (buffer `buf`, issued 2 iters ago) must have landed
    if (it == ntiles - 1) {
      asm volatile("s_waitcnt vmcnt(0)" ::: "memory");
    } else {
      asm volatile("s_waitcnt vmcnt(2)" ::: "memory");
    }
    __builtin_amdgcn_s_barrier();   // all waves' loads for `buf` landed; prev compute done
    if (it + 2 < ntiles) {
      int nbuf = buf + 2;
      if (nbuf >= 3) nbuf -= 3;
      STAGE(kbeg + (it + 2) * 64, nbuf)
    }

    const int k0 = kbeg + it * 64;
    if (k0 <= iw + 15) {
      const char* KsT = (const char*)Ks + buf * 8192;
      const char* VsT = (const char*)Vs + buf * 8192;

      f32x4 sfr[4];
      __builtin_amdgcn_s_setprio(1);
#pragma unroll
      for (int f = 0; f < 4; ++f) {
        int key7 = ((f & 1) * 4) | (c & 3);
        int key = (f >> 1) * 32 + (c >> 2) * 8 + key7;
        int phi = key7 ^ (((c >> 2) & 3) << 1);
        f32x4 s = f32x4{0.f, 0.f, 0.f, 0.f};
#pragma unroll
        for (int kd = 0; kd < 2; ++kd) {
          bf16x8 kf = *reinterpret_cast<const bf16x8*>(
              KsT + key * 128 + (((kd * 4 + g) ^ phi) << 4));
          s = __builtin_amdgcn_mfma_f32_16x16x32_bf16(kf, qf[kd], s, 0, 0, 0);
        }
        sfr[f] = s;
      }
      __builtin_amdgcn_s_setprio(0);

      float pm = fmaxf(fmaxf(sfr[0][0], sfr[0][1]), fmaxf(sfr[0][2], sfr[0][3]));
#pragma unroll
      for (int f = 1; f < 4; ++f)
        pm = fmaxf(pm, fmaxf(fmaxf(sfr[f][0], sfr[f][1]), fmaxf(sfr[f][2], sfr[f][3])));
      pm = fmaxf(pm, __shfl_xor(pm, 16, 64));
      pm = fmaxf(pm, __shfl_xor(pm, 32, 64));

      if (!__all(pm <= m_run + 8.f)) {
        float mnew = fmaxf(m_run, pm);
        float corr = __builtin_amdgcn_exp2f((m_run - mnew) * L2E);
        m_run = mnew;
        m2 = mnew * L2E;
#pragma unroll
        for (int r = 0; r < 4; ++r) {
          float cr = __shfl(corr, g * 4 + r, 64);
          accl[r] *= cr;
#pragma unroll
          for (int df = 0; df < 4; ++df) acc[df][r] *= cr;
        }
      }

      const bool needC = (k0 + 63 > iw);
      const int qlane = iw + c;
      bf16x8 pa[2];
#pragma unroll
      for (int f = 0; f < 4; ++f) {
        int jb = (k0 - kbeg) + (f >> 1) * 32 + g * 8 + (f & 1) * 4;
        f32x4 pad4 = *reinterpret_cast<const f32x4*>(padf + jb);
#pragma unroll
        for (int r = 0; r < 4; ++r) {
          float pe = __builtin_amdgcn_exp2f(__builtin_fmaf(sfr[f][r], L2E, -m2)) * pad4[r];
          if (needC) pe = (kbeg + jb + r <= qlane) ? pe : 0.f;
          pa[f >> 1][(f & 1) * 4 + r] = (bf16_t)pe;
        }
      }

      __builtin_amdgcn_s_setprio(1);
#pragma unroll
      for (int ks = 0; ks < 2; ++ks) {
        accl = __builtin_amdgcn_mfma_f32_16x16x32_bf16(pa[ks], ones, accl, 0, 0, 0);
#pragma unroll
        for (int df = 0; df < 4; ++df) {
          int d = df * 16 + c;
          int phv = (d & 7) ^ (((d >> 3) & 3) << 1);
          bf16x8 vf = *reinterpret_cast<const bf16x8*>(
              VsT + d * 128 + (((ks * 4 + g) ^ phv) << 4));
          acc[df] = __builtin_amdgcn_mfma_f32_16x16x32_bf16(pa[ks], vf, acc[df], 0, 0, 0);
        }
      }
      __builtin_amdgcn_s_setprio(0);
    }

    ++buf;
    if (buf == 3) buf = 0;
  }
#undef STAGE

  if (nch == 1) {
    // single-chunk Q (Q<4): normalize and write Ob directly; row 0 owned by row-0 path
#pragma unroll
    for (int r = 0; r < 4; ++r) {
      float inv = 1.0f / accl[r];
      int row = w * 16 + g * 4 + r;
#pragma unroll
      for (int df = 0; df < 4; ++df) {
        if (q0 + row != 0)
          Ob[(size_t)(q0 + row) * DIM + h * DH + df * 16 + c] = (bf16_t)(acc[df][r] * inv);
      }
    }
    return;
  }

  // write unnormalized partial (merged by separate k_merge kernel)
  char* pb = part + (size_t)(h * PART_SLOTS + (slot - 4)) * PART_STRIDE;
  bf16_t* po = (bf16_t*)pb;
  float* pmo = (float*)(pb + 16384);
  float* plo = (float*)(pb + 16896);
  float mq[4];
#pragma unroll
  for (int r = 0; r < 4; ++r) mq[r] = __shfl(m2, g * 4 + r, 64);
#pragma unroll
  for (int df = 0; df < 4; ++df)
#pragma unroll
    for (int r = 0; r < 4; ++r) {
      int row = w * 16 + g * 4 + r;
      po[row * 64 + df * 16 + c] = (bf16_t)acc[df][r];
    }
  if (c == 0) {
#pragma unroll
    for (int r = 0; r < 4; ++r) {
      int row = w * 16 + g * 4 + r;
      pmo[row] = mq[r];      // log2 units
      plo[row] = accl[r];
    }
  }
}

// ---- merge partials (Q>=4 only) -> Ob.  grid (12, 16): Q = bx+4 ----
__global__ __launch_bounds__(256) void k_merge(const char* __restrict__ part,
                                               bf16_t* __restrict__ Ob) {
  const int Q = blockIdx.x + 4, h = blockIdx.y;
  const int g = Q >> 2, nch = g + 1;
  const int cum = 2 * g * (g + 1) + (Q & 3) * nch - 4;
  const int t = threadIdx.x;
  const int row = t >> 1, half = t & 1;

  float acc[32];
#pragma unroll
  for (int e = 0; e < 32; ++e) acc[e] = 0.f;
  float M = -3e38f, L = 0.f;

  for (int c = 0; c < nch; ++c) {
    const char* pb = part + (size_t)(h * PART_SLOTS + cum + c) * PART_STRIDE;
    float mc = ((const float*)(pb + 16384))[row];
    float lc = ((const float*)(pb + 16896))[row];
    float Mn = fmaxf(M, mc);
    float sOld = __builtin_amdgcn_exp2f(M - Mn), sNew = __builtin_amdgcn_exp2f(mc - Mn);
    M = Mn;
    L = L * sOld + lc * sNew;
    const bf16_t* od = (const bf16_t*)pb + row * 64 + half * 32;
#pragma unroll
    for (int e4 = 0; e4 < 4; ++e4) {
      bf16x8 o8 = *reinterpret_cast<const bf16x8*>(od + e4 * 8);
#pragma unroll
      for (int e = 0; e < 8; ++e)
        acc[e4 * 8 + e] = acc[e4 * 8 + e] * sOld + (float)o8[e] * sNew;
    }
  }
  const float inv = 1.0f / L;
  bf16_t* dst = Ob + (size_t)(Q * 128 + row) * DIM + h * DH + half * 32;
#pragma unroll
  for (int e4 = 0; e4 < 4; ++e4) {
    bf16x8 r8o;
#pragma unroll
    for (int e = 0; e < 8; ++e) r8o[e] = (bf16_t)(acc[e4 * 8 + e] * inv);
    *reinterpret_cast<bf16x8*>(dst + e4 * 8) = r8o;
  }
}

// ---- host ----
extern "C" void kernel_launch(void* const* d_in, const int* in_sizes, int n_in,
                              void* d_out, int out_size, void* d_ws, size_t ws_size,
                              hipStream_t stream) {
  const float* x       = (const float*)d_in[0];
  const float* pos_sin = (const float*)d_in[1];
  const float* pos_cos = (const float*)d_in[2];
  const int*   mask    = (const int*)d_in[3];
  const float* ln_s    = (const float*)d_in[4];
  const float* ln_b    = (const float*)d_in[5];
  const float* w_qkv   = (const float*)d_in[6];
  const float* w_out   = (const float*)d_in[7];
  const float* b_out   = (const float*)d_in[8];
  float* out = (float*)d_out;

  if (ws_size < 33554432u) return;

  char* ws = (char*)d_ws;
  bf16_t* Qp   = (bf16_t*)(ws + 0);           //  4 MiB: 2048x1024
  bf16_t* Kp   = (bf16_t*)(ws + 4194304);     //  4 MiB: 16x2048x64
  bf16_t* Vt   = (bf16_t*)(ws + 8388608);     //  4 MiB: 16x64x2048
  bf16_t* Ob   = (bf16_t*)(ws + 12582912);    //  4 MiB: 2048x1024
  bf16_t* Wot  = (bf16_t*)(ws + 16777216);    //  2 MiB, alive whole run
  bf16_t* xn   = (bf16_t*)(ws + 18874368);    //  4 MiB, dead after QKV gemm
  bf16_t* Wqt  = (bf16_t*)(ws + 23068672);    //  6 MiB, dead after QKV gemm
  char*   part = ws + 18874368;               // 10.03 MiB (16*36*17408), overlays xn/Wqt

  k_ln_tc<<<NTOK + 768 + 256, 256, 0, stream>>>(x, ln_s, ln_b, xn, w_qkv, Wqt, w_out, Wot);
  k_gemm_qkv<<<dim3(16, 24), 256, 0, stream>>>(xn, Wqt, Qp, Kp, Vt, pos_sin, pos_cos);
  k_attn_part<<<16 * (SLOTS_PER_HEAD + 1), 512, 0, stream>>>(Qp, Kp, Vt, mask, part, Ob);
  k_merge<<<dim3(12, 16), 256, 0, stream>>>(part, Ob);
  k_gemm64<<<dim3(32, 16), 256, 0, stream>>>(Ob, Wot, out, b_out, NTOK, DIM, DIM);
}